// Round 7
// baseline (291.085 us; speedup 1.0000x reference)
//
#include <hip/hip_runtime.h>

// B=4, T=2048, C=1024, H=16, D=64. Device buffers f32 (mask int32).
// R17 = R16 with the QKV GEMM replaced by gemm8p, a plain-HIP port of the
// m201 8-phase 256^2 structure (1563 TF @4k, refcheck'd in learn_hip):
//   256x256 tile, BK=64, 8 waves (2Mx4N, per-wave 128x64, acc 8x4),
//   2 LDS tile-buffers (128KB dynamic). Per K-tile: 4 phases x 16 MFMA.
//   Prefetch tile t+1: P1 issues A-halves g0,g2; P2 issues B g0..g3;
//   P3 issues A g1,g3. Guards (each = per-wave vmcnt + all-waves barrier):
//     P3-end: vmcnt(2) -> Ag0,Ag2,B* of t+1 landed (P0(t+1) reads those);
//             last pair (Ag1,Ag3) stays in flight ACROSS the barrier.
//     P0-end: vmcnt(0) -> Ag1,Ag3 landed (issued ~2 phases ago, ~free;
//             P0 issues no GLDS so nothing fresh is drained).
//   WAR (GLDS overwriting the buffer read last iter) covered by P3 barrier.
//   setprio(1) around each 16-MFMA cluster (T5, +21-25% on 8-phase).
// proj GEMM: R16 gemmT<128,64,64,1> (3-buf BK=32 counted-vmcnt) unchanged.
// attn: frozen at R12 (92us, MfmaUtil 31, conflicts 0).

#define TT 2048
#define CC 1024
#define HH 16
#define DD 64
#define BB 4

typedef unsigned short u16;
typedef unsigned int u32;
typedef __attribute__((ext_vector_type(8))) short bf16x8;
typedef __attribute__((ext_vector_type(4))) float f32x4;
typedef __attribute__((ext_vector_type(4))) u32 u32x4;

#if __has_builtin(__builtin_amdgcn_exp2f)
#define EXP2(x) __builtin_amdgcn_exp2f(x)
#else
#define EXP2(x) __expf((x) * 0.6931471805599453f)
#endif

__device__ __forceinline__ u16 f2bf(float f) {
    u32 u = __builtin_bit_cast(u32, f);
    u += 0x7FFFu + ((u >> 16) & 1u);
    return (u16)(u >> 16);
}
__device__ __forceinline__ u32 pk2(float a, float b) {
    u32 ua = __builtin_bit_cast(u32, a); ua += 0x7FFFu + ((ua >> 16) & 1u);
    u32 ub = __builtin_bit_cast(u32, b); ub += 0x7FFFu + ((ub >> 16) & 1u);
    return __builtin_amdgcn_perm(ub, ua, 0x07060302);  // {hi16(ub), hi16(ua)}
}
__device__ __forceinline__ u32 cvtpk(float lo, float hi) {
    u32 r;
    asm("v_cvt_pk_bf16_f32 %0, %1, %2" : "=v"(r) : "v"(lo), "v"(hi));
    return r;
}

#define GLDS(g, l) __builtin_amdgcn_global_load_lds( \
    (const __attribute__((address_space(1))) void*)(g), \
    (__attribute__((address_space(3))) void*)(l), 16, 0, 0)

#define PH_SYNC() { __builtin_amdgcn_sched_barrier(0); \
                    __builtin_amdgcn_s_barrier(); \
                    __builtin_amdgcn_sched_barrier(0); }

// ---------------------------------------------------------------------------
__global__ __launch_bounds__(256) void wcvt(const float* __restrict__ s,
                                            u16* __restrict__ d, int n8) {
    const int i = blockIdx.x * 256 + threadIdx.x;
    if (i < n8) {
        const float4 f0 = ((const float4*)s)[2 * i];
        const float4 f1 = ((const float4*)s)[2 * i + 1];
        uint4 w;
        w.x = pk2(f0.x, f0.y); w.y = pk2(f0.z, f0.w);
        w.z = pk2(f1.x, f1.y); w.w = pk2(f1.z, f1.w);
        ((uint4*)d)[i] = w;
    }
}

// Fused f32->bf16: x (4096 blocks) + Wq/Wk/Wv (3x512 blocks).
__global__ __launch_bounds__(256) void wcvtA(const float* __restrict__ x,
                                             const float* __restrict__ Wq,
                                             const float* __restrict__ Wk,
                                             const float* __restrict__ Wv,
                                             u16* __restrict__ xb,
                                             u16* __restrict__ Wq16,
                                             u16* __restrict__ Wk16,
                                             u16* __restrict__ Wv16) {
    const int bid = blockIdx.x;
    const float* s; u16* d; int i;
    if (bid < 4096) {
        s = x; d = xb; i = bid * 256 + threadIdx.x;
    } else {
        const int t = bid - 4096;
        const int which = t >> 9, sub = t & 511;
        s = (which == 0) ? Wq : (which == 1) ? Wk : Wv;
        d = (which == 0) ? Wq16 : (which == 1) ? Wk16 : Wv16;
        i = sub * 256 + threadIdx.x;
    }
    const float4 f0 = ((const float4*)s)[2 * i];
    const float4 f1 = ((const float4*)s)[2 * i + 1];
    uint4 w;
    w.x = pk2(f0.x, f0.y); w.y = pk2(f0.z, f0.w);
    w.z = pk2(f1.x, f1.y); w.w = pk2(f1.z, f1.w);
    ((uint4*)d)[i] = w;
}

// ---------------------------------------------------------------------------
// QKV GEMM, 8-phase 256^2 (m201 port). out = A[8192,1024] @ W[3072,1024]^T
// + bias -> Q rowmajor | K rowmajor | V^T [B,H,D,T], all bf16.
// ---------------------------------------------------------------------------
__global__ __launch_bounds__(512) void gemm8p(const u16* __restrict__ Ag,
                                              const u16* __restrict__ Wb,
                                              const float* __restrict__ b0,
                                              const float* __restrict__ b1,
                                              const float* __restrict__ b2,
                                              u16* __restrict__ outQ,
                                              u16* __restrict__ outK,
                                              u16* __restrict__ outV) {
    extern __shared__ u16 lds[];   // A: [2][16384] | B(+32768): [2][16384]
    const int tid  = threadIdx.x;
    const int wave = tid >> 6, lane = tid & 63;
    const int quad = lane >> 4, l16 = lane & 15;
    const int wr = wave >> 2, wc = wave & 3;
    constexpr int NT = CC / 64;    // 16 K-tiles

    // bijective XCD chunk swizzle over 12x32 = 384 blocks
    const int bid0 = blockIdx.y * 12 + blockIdx.x;
    const int bid  = (bid0 & 7) * 48 + (bid0 >> 3);
    const int bn = (bid % 12) * 256, bm = (bid / 12) * 256;

    // staging: slot c -> row=c>>3 (0..255), pos=c&7; global chunk = pos^ (row&7)
    // group g covers rows [64g, 64g+64)
    u32 aOff[4], bOff[4]; int dstOff[4];
#pragma unroll
    for (int g = 0; g < 4; g++) {
        const int c = g * 512 + tid;
        const int row = c >> 3;
        const int kc = (c & 7) ^ (row & 7);
        aOff[g] = (u32)(bm + row) * CC + kc * 8;
        bOff[g] = (u32)(bn + row) * CC + kc * 8;
        dstOff[g] = c * 8;
    }

    // fragment read offsets (elems, ks=0); ks=1 = ^32 (pos bit-2 flip * 8)
    int aO[8], bO[4];
#pragma unroll
    for (int i = 0; i < 8; i++) {
        const int row = wr * 128 + i * 16 + l16;
        aO[i] = row * 64 + (quad ^ (row & 7)) * 8;
    }
#pragma unroll
    for (int j = 0; j < 4; j++) {
        const int row = wc * 64 + j * 16 + l16;
        bO[j] = row * 64 + (quad ^ (row & 7)) * 8;
    }

    f32x4 acc[8][4] = {};

    // prologue: stage tile 0 in guard order [Ag0,Ag2, Bg0..3, Ag1,Ag3]
    {
        u16* An = lds;
        u16* Bn = lds + 32768;
        GLDS(&Ag[(size_t)aOff[0]], &An[dstOff[0]]);
        GLDS(&Ag[(size_t)aOff[2]], &An[dstOff[2]]);
#pragma unroll
        for (int g = 0; g < 4; g++) GLDS(&Wb[(size_t)bOff[g]], &Bn[dstOff[g]]);
        GLDS(&Ag[(size_t)aOff[1]], &An[dstOff[1]]);
        GLDS(&Ag[(size_t)aOff[3]], &An[dstOff[3]]);
        asm volatile("s_waitcnt vmcnt(2)" ::: "memory");
        PH_SYNC();
    }

#pragma unroll 1
    for (int t = 0; t < NT; t++) {
        const u16* Ab = lds + (t & 1) * 16384;
        const u16* Bb = lds + 32768 + (t & 1) * 16384;
        u16* An = lds + ((t & 1) ^ 1) * 16384;
        u16* Bn = lds + 32768 + ((t & 1) ^ 1) * 16384;
        const int k1 = (t + 1) * 64;
        const bool pf = (t + 1 < NT);

        bf16x8 af[4], bfr[4];

        // ---- P0: read af[0..3]ks0 + bfr ks0; 16 MFMA; no GLDS ----
#pragma unroll
        for (int j = 0; j < 4; j++) bfr[j] = *(const bf16x8*)&Bb[bO[j]];
#pragma unroll
        for (int i = 0; i < 4; i++) af[i] = *(const bf16x8*)&Ab[aO[i]];
        asm volatile("s_waitcnt lgkmcnt(0)" ::: "memory");
        __builtin_amdgcn_sched_barrier(0);
        __builtin_amdgcn_s_setprio(1);
#pragma unroll
        for (int i = 0; i < 4; i++)
#pragma unroll
            for (int j = 0; j < 4; j++)
                acc[i][j] = __builtin_amdgcn_mfma_f32_16x16x32_bf16(af[i], bfr[j], acc[i][j], 0, 0, 0);
        __builtin_amdgcn_s_setprio(0);
        // drain prev-iter leftovers (Ag1,Ag3 of tile t), ~2 phases old
        asm volatile("s_waitcnt vmcnt(0)" ::: "memory");
        PH_SYNC();

        // ---- P1: GLDS Ag0,Ag2(t+1); read af[4..7]ks0; 16 MFMA ----
        if (pf) {
            GLDS(&Ag[(size_t)aOff[0] + k1], &An[dstOff[0]]);
            GLDS(&Ag[(size_t)aOff[2] + k1], &An[dstOff[2]]);
        }
#pragma unroll
        for (int i = 0; i < 4; i++) af[i] = *(const bf16x8*)&Ab[aO[4 + i]];
        asm volatile("s_waitcnt lgkmcnt(0)" ::: "memory");
        __builtin_amdgcn_sched_barrier(0);
        __builtin_amdgcn_s_setprio(1);
#pragma unroll
        for (int i = 0; i < 4; i++)
#pragma unroll
            for (int j = 0; j < 4; j++)
                acc[4 + i][j] = __builtin_amdgcn_mfma_f32_16x16x32_bf16(af[i], bfr[j], acc[4 + i][j], 0, 0, 0);
        __builtin_amdgcn_s_setprio(0);
        PH_SYNC();

        // ---- P2: GLDS Bg0..3(t+1); read bfr ks1 + af[0..3]ks1; 16 MFMA ----
        if (pf) {
#pragma unroll
            for (int g = 0; g < 4; g++)
                GLDS(&Wb[(size_t)bOff[g] + k1], &Bn[dstOff[g]]);
        }
#pragma unroll
        for (int j = 0; j < 4; j++) bfr[j] = *(const bf16x8*)&Bb[bO[j] ^ 32];
#pragma unroll
        for (int i = 0; i < 4; i++) af[i] = *(const bf16x8*)&Ab[aO[i] ^ 32];
        asm volatile("s_waitcnt lgkmcnt(0)" ::: "memory");
        __builtin_amdgcn_sched_barrier(0);
        __builtin_amdgcn_s_setprio(1);
#pragma unroll
        for (int i = 0; i < 4; i++)
#pragma unroll
            for (int j = 0; j < 4; j++)
                acc[i][j] = __builtin_amdgcn_mfma_f32_16x16x32_bf16(af[i], bfr[j], acc[i][j], 0, 0, 0);
        __builtin_amdgcn_s_setprio(0);
        PH_SYNC();

        // ---- P3: GLDS Ag1,Ag3(t+1); read af[4..7]ks1; 16 MFMA ----
        if (pf) {
            GLDS(&Ag[(size_t)aOff[1] + k1], &An[dstOff[1]]);
            GLDS(&Ag[(size_t)aOff[3] + k1], &An[dstOff[3]]);
        }
#pragma unroll
        for (int i = 0; i < 4; i++) af[i] = *(const bf16x8*)&Ab[aO[4 + i] ^ 32];
        asm volatile("s_waitcnt lgkmcnt(0)" ::: "memory");
        __builtin_amdgcn_sched_barrier(0);
        __builtin_amdgcn_s_setprio(1);
#pragma unroll
        for (int i = 0; i < 4; i++)
#pragma unroll
            for (int j = 0; j < 4; j++)
                acc[4 + i][j] = __builtin_amdgcn_mfma_f32_16x16x32_bf16(af[i], bfr[j], acc[4 + i][j], 0, 0, 0);
        __builtin_amdgcn_s_setprio(0);
        // tile boundary: next-iter P0 needs Ag0,Ag2,B* landed; keep Ag1,Ag3
        // (the newest pair) in flight across the barrier.
        if (pf) asm volatile("s_waitcnt vmcnt(2)" ::: "memory");
        else    asm volatile("s_waitcnt vmcnt(0)" ::: "memory");
        PH_SYNC();
    }

    // ---- epilogue: Q/K rowmajor bf16, V -> V^T [B,H,D,T] bf16 ----
    const int mid = bn >> 10;   // 0=Q,1=K,2=V (block-uniform; 256 | 1024)
    const float* bias = (mid == 0) ? b0 : (mid == 1) ? b1 : b2;
#pragma unroll
    for (int j = 0; j < 4; j++) {
        const int col  = bn + wc * 64 + j * 16 + l16;
        const int colL = col & (CC - 1);
        const float bv = bias[colL];
#pragma unroll
        for (int i = 0; i < 8; i++) {
            const int row0 = bm + wr * 128 + i * 16 + quad * 4;
            if (mid < 2) {
                u16* out = mid ? outK : outQ;
#pragma unroll
                for (int r = 0; r < 4; r++)
                    out[(size_t)(row0 + r) * CC + colL] = f2bf(acc[i][j][r] + bv);
            } else {
                const int hh = colL >> 6, dch = colL & 63;
                const int bb = row0 >> 11, t0 = row0 & (TT - 1);
                const size_t idx = (((size_t)bb * HH + hh) * DD + dch) * TT + t0;
                uint2 w;
                w.x = pk2(acc[i][j][0] + bv, acc[i][j][1] + bv);
                w.y = pk2(acc[i][j][2] + bv, acc[i][j][3] + bv);
                *(uint2*)&outV[idx] = w;
            }
        }
    }
}

// ---------------------------------------------------------------------------
// Proj GEMM (R16 gemmT, MODE 1 only): 256x128 tile, BK=32, 3 LDS buffers,
// stage lead 2, counted vmcnt. 72KB LDS -> 2 blocks/CU.
// ---------------------------------------------------------------------------
template <int BN, int WM, int WN, int MODE>
__global__ __launch_bounds__(512, 4) void gemmT(const u16* __restrict__ Ag,
                                                const u16* __restrict__ Bg,
                                                const float* __restrict__ b0,
                                                float* __restrict__ outF) {
    constexpr int NI = WM / 16, NJ = WN / 16;
    constexpr int WAVES_N = BN / WN;
    constexpr int BUFSZ = (256 + BN) * 32;
    constexpr int SPT = 2 + BN / 128;
    constexpr int NT = CC / 32;

    extern __shared__ u16 lds[];
    const int tid  = threadIdx.x;
    const int wave = tid >> 6, lane = tid & 63;
    const int quad = lane >> 4, l16 = lane & 15;
    const int wr = wave / WAVES_N, wc = wave & (WAVES_N - 1);

    constexpr int NBX = 1024 / BN;
    const int bid0 = blockIdx.y * NBX + blockIdx.x;
    const int chunk = (NBX * 32) >> 3;
    const int bid  = (bid0 & 7) * chunk + (bid0 >> 3);
    const int bn = (bid % NBX) * BN, bm = (bid / NBX) * 256;

    u32 aOff[2]; int aDst[2];
#pragma unroll
    for (int g = 0; g < 2; g++) {
        const int c = g * 512 + tid;
        const int row = c >> 2;
        const int kc = (c & 3) ^ ((row >> 1) & 3);
        aOff[g] = (u32)(bm + row) * CC + kc * 8;
        aDst[g] = c * 8;
    }
    u32 bOff[BN / 128]; int bDst[BN / 128];
#pragma unroll
    for (int g = 0; g < BN / 128; g++) {
        const int c = g * 512 + tid;
        const int row = c >> 2;
        const int kc = (c & 3) ^ ((row >> 1) & 3);
        bOff[g] = (u32)(bn + row) * CC + kc * 8;
        bDst[g] = 8192 + c * 8;
    }

    int aRd[NI], bRd[NJ];
#pragma unroll
    for (int i = 0; i < NI; i++) {
        const int row = wr * WM + i * 16 + l16;
        aRd[i] = row * 32 + (quad ^ ((row >> 1) & 3)) * 8;
    }
#pragma unroll
    for (int j = 0; j < NJ; j++) {
        const int row = wc * WN + j * 16 + l16;
        bRd[j] = 8192 + row * 32 + (quad ^ ((row >> 1) & 3)) * 8;
    }

    f32x4 acc[NI][NJ] = {};

#define STAGE_T(t)                                                        \
    {                                                                     \
        u16* dst = &lds[((t) % 3) * BUFSZ];                               \
        const int k0 = (t) * 32;                                          \
        _Pragma("unroll")                                                 \
        for (int g = 0; g < 2; g++)                                       \
            GLDS(&Ag[(size_t)aOff[g] + k0], &dst[aDst[g]]);               \
        _Pragma("unroll")                                                 \
        for (int g = 0; g < BN / 128; g++)                                \
            GLDS(&Bg[(size_t)bOff[g] + k0], &dst[bDst[g]]);               \
    }

#define COMPUTE_T(t)                                                      \
    {                                                                     \
        const u16* buf = &lds[((t) % 3) * BUFSZ];                         \
        bf16x8 af[NI], bfr[NJ];                                           \
        _Pragma("unroll")                                                 \
        for (int i = 0; i < NI; i++) af[i] = *(const bf16x8*)&buf[aRd[i]];\
        _Pragma("unroll")                                                 \
        for (int j = 0; j < NJ; j++) bfr[j] = *(const bf16x8*)&buf[bRd[j]];\
        __builtin_amdgcn_s_setprio(1);                                    \
        _Pragma("unroll")                                                 \
        for (int i = 0; i < NI; i++)                                      \
            _Pragma("unroll")                                             \
            for (int j = 0; j < NJ; j++)                                  \
                acc[i][j] = __builtin_amdgcn_mfma_f32_16x16x32_bf16(      \
                    af[i], bfr[j], acc[i][j], 0, 0, 0);                   \
        __builtin_amdgcn_s_setprio(0);                                    \
    }

#define WAIT_MAIN()                                                       \
    if constexpr (SPT == 3) asm volatile("s_waitcnt vmcnt(3)" ::: "memory"); \
    else                    asm volatile("s_waitcnt vmcnt(4)" ::: "memory");

    STAGE_T(0); STAGE_T(1);
    WAIT_MAIN();
    PH_SYNC();

#pragma unroll 1
    for (int t = 0; t < NT - 2; t++) {
        STAGE_T(t + 2);
        COMPUTE_T(t);
        WAIT_MAIN();
        PH_SYNC();
    }
    COMPUTE_T(NT - 2);
    asm volatile("s_waitcnt vmcnt(0)" ::: "memory");
    PH_SYNC();
    COMPUTE_T(NT - 1);

#undef STAGE_T
#undef COMPUTE_T
#undef WAIT_MAIN

#pragma unroll
    for (int j = 0; j < NJ; j++) {
        const int col = bn + wc * WN + j * 16 + l16;
        const float bv = b0[col];
#pragma unroll
        for (int i = 0; i < NI; i++) {
            const int row0 = bm + wr * WM + i * 16 + quad * 4;
#pragma unroll
            for (int r = 0; r < 4; r++)
                outF[(size_t)(row0 + r) * CC + col] = acc[i][j][r] + bv;
        }
    }
}

// ---------------------------------------------------------------------------
// Flash attention (frozen since R12). Block = (qt,h,b): 256 q-rows,
// 8 waves x 32 rows. Swapped QK^T, in-register P, ks-split softmax/PV,
// double-buffered GLDS, single raw barrier per tile.
// ---------------------------------------------------------------------------
__global__ __launch_bounds__(512) void attn(const u16* __restrict__ Q,
                                            const u16* __restrict__ Kb,
                                            const u16* __restrict__ Vt,
                                            const int* __restrict__ mask,
                                            u16* __restrict__ Y) {
    const int b = blockIdx.z, h = blockIdx.y, qt = blockIdx.x;
    const int tid  = threadIdx.x;
    const int wave = tid >> 6, lane = tid & 63;
    const int quad = lane >> 4, l16 = lane & 15;
    const int qrow0 = qt * 256 + wave * 32;

    __shared__ u16 Ks[2][64 * 64];              // [key][dim]
    __shared__ u16 Vs[2][64 * 64];              // [d][key]
    __shared__ __align__(16) float bias_lds[TT];  // 0 or -1e38 per key

    const size_t qb = ((size_t)b * TT + qrow0) * CC + h * DD;

    bf16x8 qf[2][2];
#pragma unroll
    for (int m = 0; m < 2; m++)
#pragma unroll
        for (int ks = 0; ks < 2; ks++)
            qf[m][ks] = *(const bf16x8*)&Q[qb + (size_t)(m * 16 + l16) * CC + ks * 32 + quad * 8];

    {
        const int i = tid * 4;
        const int4 m0 = *(const int4*)&mask[b * TT + i];
        bias_lds[i + 0] = m0.x ? 0.f : -1e38f;
        bias_lds[i + 1] = m0.y ? 0.f : -1e38f;
        bias_lds[i + 2] = m0.z ? 0.f : -1e38f;
        bias_lds[i + 3] = m0.w ? 0.f : -1e38f;
    }

    const int c0 = tid;
    const int r0 = c0 >> 3;
    const int kp0 = (c0 & 7) ^ ((((r0 >> 3) & 1) << 2) | (r0 & 3));
    const int vp0 = (c0 & 7) ^ (r0 & 7);
    const u16* kgp = Kb + ((size_t)b * TT) * CC + h * DD;
    const u16* vgp = Vt + ((size_t)(b * HH + h) * DD) * TT;

    const int rowA = ((l16 >> 2) << 3) | (l16 & 3);
    const int s0k  = (((l16 >> 2) & 1) << 2) | (l16 & 3);

    f32x4 o[2][4] = {};
    float lsum[2] = {};
    const float SC = 0.18033688011112042f;   // 0.125 * log2(e)

    GLDS(&kgp[(size_t)r0 * CC + kp0 * 8], &Ks[0][c0 * 8]);
    GLDS(&vgp[(size_t)r0 * TT + vp0 * 8], &Vs[0][c0 * 8]);
    asm volatile("s_waitcnt vmcnt(0) lgkmcnt(0)" ::: "memory");
    __builtin_amdgcn_s_barrier();
    __builtin_amdgcn_sched_barrier(0);

#pragma unroll 1
    for (int kt = 0; kt < TT; kt += 64) {
        const int cur = (kt >> 6) & 1;
        const u16* Kc = &Ks[cur][0];
        const u16* Vc = &Vs[cur][0];

        if (kt + 64 < TT) {
            const int nxt = cur ^ 1;
            GLDS(&kgp[(size_t)(kt + 64 + r0) * CC + kp0 * 8], &Ks[nxt][c0 * 8]);
            GLDS(&vgp[(size_t)r0 * TT + kt + 64 + vp0 * 8], &Vs[nxt][c0 * 8]);
        }

        const f32x4 bA = *(const f32x4*)&bias_lds[kt + quad * 8];
        const f32x4 bB = *(const f32x4*)&bias_lds[kt + quad * 8 + 4];
        const f32x4 bC = *(const f32x4*)&bias_lds[kt + 32 + quad * 8];
        const f32x4 bD = *(const f32x4*)&bias_lds[kt + 32 + quad * 8 + 4];

        f32x4 s2[2][4] = {};
        __builtin_amdgcn_s_setprio(1);
#pragma unroll
        for (int n = 0; n < 4; n++) {
            const int rowK = rowA + (n & 1) * 4 + (n >> 1) * 32;
#pragma unroll
            for (int ks = 0; ks < 2; ks++) {
                const int pos = ((ks << 2) + quad) ^ s0k;
                const bf16x8 kf = *(const bf16x8*)&Kc[rowK * 64 + pos * 8];
#pragma unroll
                for (int m = 0; m < 2; m++)
                    s2[m][n] = __builtin_amdgcn_mfma_f32_16x16x32_bf16(kf, qf[m][ks], s2[m][n], 0, 0, 0);
            }
        }
        __builtin_amdgcn_s_setprio(0);

#pragma unroll
        for (int ks = 0; ks < 2; ks++) {
            bf16x8 pf[2];
#pragma unroll
            for (int m = 0; m < 2; m++) {
                u32 pw[4];
#pragma unroll
                for (int nn = 0; nn < 2; nn++) {
                    const int n = 2 * ks + nn;
                    const f32x4 bv = (n == 0) ? bA : (n == 1) ? bB : (n == 2) ? bC : bD;
                    const float p0 = EXP2(fmaf(s2[m][n][0], SC, bv[0]));
                    const float p1 = EXP2(fmaf(s2[m][n][1], SC, bv[1]));
                    const float p2 = EXP2(fmaf(s2[m][n][2], SC, bv[2]));
                    const float p3 = EXP2(fmaf(s2[m][n][3], SC, bv[3]));
                    lsum[m] += (p0 + p1) + (p2 + p3);
                    pw[2 * nn]     = cvtpk(p0, p1);
                    pw[2 * nn + 1] = cvtpk(p2, p3);
                }
                const u32x4 t = { pw[0], pw[1], pw[2], pw[3] };
                pf[m] = __builtin_bit_cast(bf16x8, t);
            }
            __builtin_amdgcn_s_setprio(1);
#pragma unroll
            for (int dt = 0; dt < 4; dt++) {
                const int vrow = dt * 16 + l16;
                const int pos = ((ks << 2) + quad) ^ (vrow & 7);
                const bf16x8 vf = *(const bf16x8*)&Vc[vrow * 64 + pos * 8];
#pragma unroll
                for (int m = 0; m < 2; m++)
                    o[m][dt] = __builtin_amdgcn_mfma_f32_16x16x32_bf16(pf[m], vf, o[m][dt], 0, 0, 0);
            }
            __builtin_amdgcn_s_setprio(0);
        }

        asm volatile("s_waitcnt vmcnt(0)" ::: "memory");
        __builtin_amdgcn_sched_barrier(0);
        __builtin_amdgcn_s_barrier();
    }

#pragma unroll
    for (int m = 0; m < 2; m++) {
        lsum[m] += __shfl_xor(lsum[m], 16, 64);
        lsum[m] += __shfl_xor(lsum[m], 32, 64);
    }

#pragma unroll
    for (int m = 0; m < 2; m++) {
        float inv[4];
#pragma unroll
        for (int r = 0; r < 4; r++)
            inv[r] = 1.0f / __shfl(lsum[m], quad * 4 + r, 64);
#pragma unroll
        for (int dt = 0; dt < 4; dt++)
#pragma unroll
            for (int r = 0; r < 4; r++)
                Y[qb + (size_t)(m * 16 + quad * 4 + r) * CC + dt * 16 + l16] = f2bf(o[m][dt][r] * inv[r]);
    }
}

// ---------------------------------------------------------------------------
extern "C" void kernel_launch(void* const* d_in, const int* in_sizes, int n_in,
                              void* d_out, int out_size, void* d_ws, size_t ws_size,
                              hipStream_t stream) {
    const float* x    = (const float*)d_in[0];
    const int*   mask = (const int*)d_in[1];
    const float* Wq   = (const float*)d_in[2];
    const float* bq   = (const float*)d_in[3];
    const float* Wk   = (const float*)d_in[4];
    const float* bk   = (const float*)d_in[5];
    const float* Wv   = (const float*)d_in[6];
    const float* bv   = (const float*)d_in[7];
    const float* Wp   = (const float*)d_in[8];
    const float* bp   = (const float*)d_in[9];

    u16* ws = (u16*)d_ws;
    const size_t sz = (size_t)BB * TT * CC;     // 8,388,608 elems
    u16* Qb   = ws;              // Q; attn writes O here
    u16* Kbuf = ws + sz;         // K; reused for bf16 Wp after attn
    u16* Vtb  = ws + 2 * sz;     // V^T [B,H,D,T]   (ws total 48 MiB)

    u16* xb   = (u16*)d_out;     // squatters in d_out (dead by proj GEMM)
    u16* Wq16 = xb + sz;
    u16* Wk16 = Wq16 + (size_t)CC * CC;
    u16* Wv16 = Wk16 + (size_t)CC * CC;   // Wq16..Wv16 contiguous = W[3072][1024]

    static bool inited = false;
    if (!inited) {
        (void)hipFuncSetAttribute((const void*)gemm8p,
                                  hipFuncAttributeMaxDynamicSharedMemorySize, 131072);
        (void)hipFuncSetAttribute((const void*)gemmT<128, 64, 64, 1>,
                                  hipFuncAttributeMaxDynamicSharedMemorySize, 73728);
        inited = true;
    }

    const int W8 = CC * CC / 8;      // 131072

    wcvtA<<<5632, 256, 0, stream>>>(x, Wq, Wk, Wv, xb, Wq16, Wk16, Wv16);

    gemm8p<<<dim3(12, 32), 512, 131072, stream>>>(
        xb, Wq16, bq, bk, bv, Qb, Kbuf, Vtb);

    attn<<<dim3(TT / 256, HH, BB), 512, 0, stream>>>(Qb, Kbuf, Vtb, mask, Qb);

    wcvt<<<512, 256, 0, stream>>>(Wp, Kbuf, W8);   // Kbuf dead after attn

    gemmT<128, 64, 64, 1><<<dim3(8, 32), 512, 73728, stream>>>(
        Qb, Kbuf, bp, (float*)d_out);
}

// Round 8
// 286.573 us; speedup vs baseline: 1.0157x; 1.0157x over previous
//
#include <hip/hip_runtime.h>

// B=4, T=2048, C=1024, H=16, D=64. Device buffers f32 (mask int32).
// R18 = R17 with two fixes:
//   - gemm4p (QKV): R17's verified 256^2 geometry, rescheduled. ALL 8 GLDS
//     for tile t+1 issue at P0 (dest buffer's last reader was P3 of t-1,
//     behind the tile barrier); the ONLY memory wait is vmcnt(0) at P3-end,
//     on loads 3 phases (~1860 cyc) old -> free. R17's per-phase waits hit
//     1-phase-old loads (<HBM latency) and stalled every tile.
//     4 phases x 16 MFMA, per-phase barrier, lgkmcnt(0)+sched_barrier before
//     each MFMA cluster (rule 18), setprio around clusters.
//   - proj gemmT re-templated <BM=128,BN=128,WM=32,WN=64>: 512 blocks,
//     48KB LDS -> 3 blocks/CU (R16's proj ran 256 blocks = 1/CU lockstep,
//     the exact starvation R16 fixed for QKV).
// attn: frozen at R12 (92us). wcvtA/wcvt unchanged.

#define TT 2048
#define CC 1024
#define HH 16
#define DD 64
#define BB 4

typedef unsigned short u16;
typedef unsigned int u32;
typedef __attribute__((ext_vector_type(8))) short bf16x8;
typedef __attribute__((ext_vector_type(4))) float f32x4;
typedef __attribute__((ext_vector_type(4))) u32 u32x4;

#if __has_builtin(__builtin_amdgcn_exp2f)
#define EXP2(x) __builtin_amdgcn_exp2f(x)
#else
#define EXP2(x) __expf((x) * 0.6931471805599453f)
#endif

__device__ __forceinline__ u16 f2bf(float f) {
    u32 u = __builtin_bit_cast(u32, f);
    u += 0x7FFFu + ((u >> 16) & 1u);
    return (u16)(u >> 16);
}
__device__ __forceinline__ u32 pk2(float a, float b) {
    u32 ua = __builtin_bit_cast(u32, a); ua += 0x7FFFu + ((ua >> 16) & 1u);
    u32 ub = __builtin_bit_cast(u32, b); ub += 0x7FFFu + ((ub >> 16) & 1u);
    return __builtin_amdgcn_perm(ub, ua, 0x07060302);  // {hi16(ub), hi16(ua)}
}
__device__ __forceinline__ u32 cvtpk(float lo, float hi) {
    u32 r;
    asm("v_cvt_pk_bf16_f32 %0, %1, %2" : "=v"(r) : "v"(lo), "v"(hi));
    return r;
}

#define GLDS(g, l) __builtin_amdgcn_global_load_lds( \
    (const __attribute__((address_space(1))) void*)(g), \
    (__attribute__((address_space(3))) void*)(l), 16, 0, 0)

#define PH_SYNC() { __builtin_amdgcn_sched_barrier(0); \
                    __builtin_amdgcn_s_barrier(); \
                    __builtin_amdgcn_sched_barrier(0); }

// ---------------------------------------------------------------------------
__global__ __launch_bounds__(256) void wcvt(const float* __restrict__ s,
                                            u16* __restrict__ d, int n8) {
    const int i = blockIdx.x * 256 + threadIdx.x;
    if (i < n8) {
        const float4 f0 = ((const float4*)s)[2 * i];
        const float4 f1 = ((const float4*)s)[2 * i + 1];
        uint4 w;
        w.x = pk2(f0.x, f0.y); w.y = pk2(f0.z, f0.w);
        w.z = pk2(f1.x, f1.y); w.w = pk2(f1.z, f1.w);
        ((uint4*)d)[i] = w;
    }
}

// Fused f32->bf16: x (4096 blocks) + Wq/Wk/Wv (3x512 blocks).
__global__ __launch_bounds__(256) void wcvtA(const float* __restrict__ x,
                                             const float* __restrict__ Wq,
                                             const float* __restrict__ Wk,
                                             const float* __restrict__ Wv,
                                             u16* __restrict__ xb,
                                             u16* __restrict__ Wq16,
                                             u16* __restrict__ Wk16,
                                             u16* __restrict__ Wv16) {
    const int bid = blockIdx.x;
    const float* s; u16* d; int i;
    if (bid < 4096) {
        s = x; d = xb; i = bid * 256 + threadIdx.x;
    } else {
        const int t = bid - 4096;
        const int which = t >> 9, sub = t & 511;
        s = (which == 0) ? Wq : (which == 1) ? Wk : Wv;
        d = (which == 0) ? Wq16 : (which == 1) ? Wk16 : Wv16;
        i = sub * 256 + threadIdx.x;
    }
    const float4 f0 = ((const float4*)s)[2 * i];
    const float4 f1 = ((const float4*)s)[2 * i + 1];
    uint4 w;
    w.x = pk2(f0.x, f0.y); w.y = pk2(f0.z, f0.w);
    w.z = pk2(f1.x, f1.y); w.w = pk2(f1.z, f1.w);
    ((uint4*)d)[i] = w;
}

// ---------------------------------------------------------------------------
// QKV GEMM: 256^2, BK=64, 2 LDS buffers, 4 phases x 16 MFMA. All staging for
// tile t+1 issues at P0; single vmcnt(0) at P3-end (3 phases of lead).
// out = A[8192,1024] @ W[3072,1024]^T + bias ->
//       Q rowmajor | K rowmajor | V^T [B,H,D,T], all bf16.
// ---------------------------------------------------------------------------
__global__ __launch_bounds__(512) void gemm4p(const u16* __restrict__ Ag,
                                              const u16* __restrict__ Wb,
                                              const float* __restrict__ b0,
                                              const float* __restrict__ b1,
                                              const float* __restrict__ b2,
                                              u16* __restrict__ outQ,
                                              u16* __restrict__ outK,
                                              u16* __restrict__ outV) {
    extern __shared__ u16 lds[];   // A: [2][16384] | B(+32768): [2][16384]
    const int tid  = threadIdx.x;
    const int wave = tid >> 6, lane = tid & 63;
    const int quad = lane >> 4, l16 = lane & 15;
    const int wr = wave >> 2, wc = wave & 3;
    constexpr int NT = CC / 64;    // 16 K-tiles

    // bijective XCD chunk swizzle over 12x32 = 384 blocks
    const int bid0 = blockIdx.y * 12 + blockIdx.x;
    const int bid  = (bid0 & 7) * 48 + (bid0 >> 3);
    const int bn = (bid % 12) * 256, bm = (bid / 12) * 256;

    // staging: slot c -> row=c>>3 (0..255), pos=c&7; global chunk = pos^(row&7)
    u32 aOff[4], bOff[4]; int dstOff[4];
#pragma unroll
    for (int g = 0; g < 4; g++) {
        const int c = g * 512 + tid;
        const int row = c >> 3;
        const int kc = (c & 7) ^ (row & 7);
        aOff[g] = (u32)(bm + row) * CC + kc * 8;
        bOff[g] = (u32)(bn + row) * CC + kc * 8;
        dstOff[g] = c * 8;
    }

    // fragment read offsets (elems, ks=0); ks=1 = ^32
    int aO[8], bO[4];
#pragma unroll
    for (int i = 0; i < 8; i++) {
        const int row = wr * 128 + i * 16 + l16;
        aO[i] = row * 64 + (quad ^ (row & 7)) * 8;
    }
#pragma unroll
    for (int j = 0; j < 4; j++) {
        const int row = wc * 64 + j * 16 + l16;
        bO[j] = row * 64 + (quad ^ (row & 7)) * 8;
    }

    f32x4 acc[8][4] = {};

    // prologue: stage tile 0, drain, sync
    {
        u16* An = lds;
        u16* Bn = lds + 32768;
#pragma unroll
        for (int g = 0; g < 4; g++) GLDS(&Ag[(size_t)aOff[g]], &An[dstOff[g]]);
#pragma unroll
        for (int g = 0; g < 4; g++) GLDS(&Wb[(size_t)bOff[g]], &Bn[dstOff[g]]);
        asm volatile("s_waitcnt vmcnt(0)" ::: "memory");
        PH_SYNC();
    }

#pragma unroll 1
    for (int t = 0; t < NT; t++) {
        const u16* Ab = lds + (t & 1) * 16384;
        const u16* Bb = lds + 32768 + (t & 1) * 16384;
        u16* An = lds + ((t & 1) ^ 1) * 16384;
        u16* Bn = lds + 32768 + ((t & 1) ^ 1) * 16384;
        const int k1 = (t + 1) * 64;
        const bool pf = (t + 1 < NT);

        bf16x8 af[4], bfr[4];

        // ---- P0: issue ALL staging for t+1; MFMA ks0 low half ----
        if (pf) {
#pragma unroll
            for (int g = 0; g < 4; g++)
                GLDS(&Ag[(size_t)aOff[g] + k1], &An[dstOff[g]]);
#pragma unroll
            for (int g = 0; g < 4; g++)
                GLDS(&Wb[(size_t)bOff[g] + k1], &Bn[dstOff[g]]);
        }
#pragma unroll
        for (int j = 0; j < 4; j++) bfr[j] = *(const bf16x8*)&Bb[bO[j]];
#pragma unroll
        for (int i = 0; i < 4; i++) af[i] = *(const bf16x8*)&Ab[aO[i]];
        asm volatile("s_waitcnt lgkmcnt(0)" ::: "memory");
        __builtin_amdgcn_sched_barrier(0);
        __builtin_amdgcn_s_setprio(1);
#pragma unroll
        for (int i = 0; i < 4; i++)
#pragma unroll
            for (int j = 0; j < 4; j++)
                acc[i][j] = __builtin_amdgcn_mfma_f32_16x16x32_bf16(af[i], bfr[j], acc[i][j], 0, 0, 0);
        __builtin_amdgcn_s_setprio(0);
        PH_SYNC();

        // ---- P1: MFMA ks0 high half (bfr ks0 reused) ----
#pragma unroll
        for (int i = 0; i < 4; i++) af[i] = *(const bf16x8*)&Ab[aO[4 + i]];
        asm volatile("s_waitcnt lgkmcnt(0)" ::: "memory");
        __builtin_amdgcn_sched_barrier(0);
        __builtin_amdgcn_s_setprio(1);
#pragma unroll
        for (int i = 0; i < 4; i++)
#pragma unroll
            for (int j = 0; j < 4; j++)
                acc[4 + i][j] = __builtin_amdgcn_mfma_f32_16x16x32_bf16(af[i], bfr[j], acc[4 + i][j], 0, 0, 0);
        __builtin_amdgcn_s_setprio(0);
        PH_SYNC();

        // ---- P2: MFMA ks1 low half ----
#pragma unroll
        for (int j = 0; j < 4; j++) bfr[j] = *(const bf16x8*)&Bb[bO[j] ^ 32];
#pragma unroll
        for (int i = 0; i < 4; i++) af[i] = *(const bf16x8*)&Ab[aO[i] ^ 32];
        asm volatile("s_waitcnt lgkmcnt(0)" ::: "memory");
        __builtin_amdgcn_sched_barrier(0);
        __builtin_amdgcn_s_setprio(1);
#pragma unroll
        for (int i = 0; i < 4; i++)
#pragma unroll
            for (int j = 0; j < 4; j++)
                acc[i][j] = __builtin_amdgcn_mfma_f32_16x16x32_bf16(af[i], bfr[j], acc[i][j], 0, 0, 0);
        __builtin_amdgcn_s_setprio(0);
        PH_SYNC();

        // ---- P3: MFMA ks1 high half; wait t+1 staging (3 phases old) ----
#pragma unroll
        for (int i = 0; i < 4; i++) af[i] = *(const bf16x8*)&Ab[aO[4 + i] ^ 32];
        asm volatile("s_waitcnt lgkmcnt(0)" ::: "memory");
        __builtin_amdgcn_sched_barrier(0);
        __builtin_amdgcn_s_setprio(1);
#pragma unroll
        for (int i = 0; i < 4; i++)
#pragma unroll
            for (int j = 0; j < 4; j++)
                acc[4 + i][j] = __builtin_amdgcn_mfma_f32_16x16x32_bf16(af[i], bfr[j], acc[4 + i][j], 0, 0, 0);
        __builtin_amdgcn_s_setprio(0);
        asm volatile("s_waitcnt vmcnt(0)" ::: "memory");
        PH_SYNC();
    }

    // ---- epilogue: Q/K rowmajor bf16, V -> V^T [B,H,D,T] bf16 ----
    const int mid = bn >> 10;   // 0=Q,1=K,2=V (block-uniform; 256 | 1024)
    const float* bias = (mid == 0) ? b0 : (mid == 1) ? b1 : b2;
#pragma unroll
    for (int j = 0; j < 4; j++) {
        const int col  = bn + wc * 64 + j * 16 + l16;
        const int colL = col & (CC - 1);
        const float bv = bias[colL];
#pragma unroll
        for (int i = 0; i < 8; i++) {
            const int row0 = bm + wr * 128 + i * 16 + quad * 4;
            if (mid < 2) {
                u16* out = mid ? outK : outQ;
#pragma unroll
                for (int r = 0; r < 4; r++)
                    out[(size_t)(row0 + r) * CC + colL] = f2bf(acc[i][j][r] + bv);
            } else {
                const int hh = colL >> 6, dch = colL & 63;
                const int bb = row0 >> 11, t0 = row0 & (TT - 1);
                const size_t idx = (((size_t)bb * HH + hh) * DD + dch) * TT + t0;
                uint2 w;
                w.x = pk2(acc[i][j][0] + bv, acc[i][j][1] + bv);
                w.y = pk2(acc[i][j][2] + bv, acc[i][j][3] + bv);
                *(uint2*)&outV[idx] = w;
            }
        }
    }
}

// ---------------------------------------------------------------------------
// Proj GEMM: BM x BN tile, BK=32, 3 LDS buffers, stage lead 2, counted vmcnt.
// <128,128,32,64>: 512 blocks, 48KB LDS -> 3 blocks/CU (TLP).
// ---------------------------------------------------------------------------
template <int BM, int BN, int WM, int WN>
__global__ __launch_bounds__(512, 4) void gemmT(const u16* __restrict__ Ag,
                                                const u16* __restrict__ Bg,
                                                const float* __restrict__ b0,
                                                float* __restrict__ outF) {
    constexpr int NI = WM / 16, NJ = WN / 16;
    constexpr int WAVES_N = BN / WN;
    constexpr int BOFF = BM * 32;                 // B region start (elems)
    constexpr int BUFSZ = (BM + BN) * 32;
    constexpr int AG = BM / 128, BG = BN / 128;   // GLDS groups per tile
    constexpr int SPT = AG + BG;
    constexpr int NT = CC / 32;
    constexpr int NBX = 1024 / BN;
    constexpr int NBY = 8192 / BM;

    extern __shared__ u16 lds[];
    const int tid  = threadIdx.x;
    const int wave = tid >> 6, lane = tid & 63;
    const int quad = lane >> 4, l16 = lane & 15;
    const int wr = wave / WAVES_N, wc = wave % WAVES_N;

    const int bid0 = blockIdx.y * NBX + blockIdx.x;
    const int chunk = (NBX * NBY) >> 3;
    const int bid  = (bid0 & 7) * chunk + (bid0 >> 3);
    const int bn = (bid % NBX) * BN, bm = (bid / NBX) * BM;

    u32 aOff[AG]; int aDst[AG];
#pragma unroll
    for (int g = 0; g < AG; g++) {
        const int c = g * 512 + tid;
        const int row = c >> 2;
        const int kc = (c & 3) ^ ((row >> 1) & 3);
        aOff[g] = (u32)(bm + row) * CC + kc * 8;
        aDst[g] = c * 8;
    }
    u32 bOff[BG]; int bDst[BG];
#pragma unroll
    for (int g = 0; g < BG; g++) {
        const int c = g * 512 + tid;
        const int row = c >> 2;
        const int kc = (c & 3) ^ ((row >> 1) & 3);
        bOff[g] = (u32)(bn + row) * CC + kc * 8;
        bDst[g] = BOFF + c * 8;
    }

    int aRd[NI], bRd[NJ];
#pragma unroll
    for (int i = 0; i < NI; i++) {
        const int row = wr * WM + i * 16 + l16;
        aRd[i] = row * 32 + (quad ^ ((row >> 1) & 3)) * 8;
    }
#pragma unroll
    for (int j = 0; j < NJ; j++) {
        const int row = wc * WN + j * 16 + l16;
        bRd[j] = BOFF + row * 32 + (quad ^ ((row >> 1) & 3)) * 8;
    }

    f32x4 acc[NI][NJ] = {};

#define STAGE_T(t)                                                        \
    {                                                                     \
        u16* dst = &lds[((t) % 3) * BUFSZ];                               \
        const int k0 = (t) * 32;                                          \
        _Pragma("unroll")                                                 \
        for (int g = 0; g < AG; g++)                                      \
            GLDS(&Ag[(size_t)aOff[g] + k0], &dst[aDst[g]]);               \
        _Pragma("unroll")                                                 \
        for (int g = 0; g < BG; g++)                                      \
            GLDS(&Bg[(size_t)bOff[g] + k0], &dst[bDst[g]]);               \
    }

#define COMPUTE_T(t)                                                      \
    {                                                                     \
        const u16* buf = &lds[((t) % 3) * BUFSZ];                         \
        bf16x8 af[NI], bfr[NJ];                                           \
        _Pragma("unroll")                                                 \
        for (int i = 0; i < NI; i++) af[i] = *(const bf16x8*)&buf[aRd[i]];\
        _Pragma("unroll")                                                 \
        for (int j = 0; j < NJ; j++) bfr[j] = *(const bf16x8*)&buf[bRd[j]];\
        __builtin_amdgcn_s_setprio(1);                                    \
        _Pragma("unroll")                                                 \
        for (int i = 0; i < NI; i++)                                      \
            _Pragma("unroll")                                             \
            for (int j = 0; j < NJ; j++)                                  \
                acc[i][j] = __builtin_amdgcn_mfma_f32_16x16x32_bf16(      \
                    af[i], bfr[j], acc[i][j], 0, 0, 0);                   \
        __builtin_amdgcn_s_setprio(0);                                    \
    }

#define WAIT_MAIN()                                                       \
    if constexpr (SPT == 2) asm volatile("s_waitcnt vmcnt(2)" ::: "memory"); \
    else if constexpr (SPT == 3) asm volatile("s_waitcnt vmcnt(3)" ::: "memory"); \
    else asm volatile("s_waitcnt vmcnt(4)" ::: "memory");

    STAGE_T(0); STAGE_T(1);
    WAIT_MAIN();
    PH_SYNC();

#pragma unroll 1
    for (int t = 0; t < NT - 2; t++) {
        STAGE_T(t + 2);
        COMPUTE_T(t);
        WAIT_MAIN();
        PH_SYNC();
    }
    COMPUTE_T(NT - 2);
    asm volatile("s_waitcnt vmcnt(0)" ::: "memory");
    PH_SYNC();
    COMPUTE_T(NT - 1);

#undef STAGE_T
#undef COMPUTE_T
#undef WAIT_MAIN

#pragma unroll
    for (int j = 0; j < NJ; j++) {
        const int col = bn + wc * WN + j * 16 + l16;
        const float bv = b0[col];
#pragma unroll
        for (int i = 0; i < NI; i++) {
            const int row0 = bm + wr * WM + i * 16 + quad * 4;
#pragma unroll
            for (int r = 0; r < 4; r++)
                outF[(size_t)(row0 + r) * CC + col] = acc[i][j][r] + bv;
        }
    }
}

// ---------------------------------------------------------------------------
// Flash attention (frozen since R12). Block = (qt,h,b): 256 q-rows,
// 8 waves x 32 rows. Swapped QK^T, in-register P, ks-split softmax/PV,
// double-buffered GLDS, single raw barrier per tile.
// ---------------------------------------------------------------------------
__global__ __launch_bounds__(512) void attn(const u16* __restrict__ Q,
                                            const u16* __restrict__ Kb,
                                            const u16* __restrict__ Vt,
                                            const int* __restrict__ mask,
                                            u16* __restrict__ Y) {
    const int b = blockIdx.z, h = blockIdx.y, qt = blockIdx.x;
    const int tid  = threadIdx.x;
    const int wave = tid >> 6, lane = tid & 63;
    const int quad = lane >> 4, l16 = lane & 15;
    const int qrow0 = qt * 256 + wave * 32;

    __shared__ u16 Ks[2][64 * 64];              // [key][dim]
    __shared__ u16 Vs[2][64 * 64];              // [d][key]
    __shared__ __align__(16) float bias_lds[TT];  // 0 or -1e38 per key

    const size_t qb = ((size_t)b * TT + qrow0) * CC + h * DD;

    bf16x8 qf[2][2];
#pragma unroll
    for (int m = 0; m < 2; m++)
#pragma unroll
        for (int ks = 0; ks < 2; ks++)
            qf[m][ks] = *(const bf16x8*)&Q[qb + (size_t)(m * 16 + l16) * CC + ks * 32 + quad * 8];

    {
        const int i = tid * 4;
        const int4 m0 = *(const int4*)&mask[b * TT + i];
        bias_lds[i + 0] = m0.x ? 0.f : -1e38f;
        bias_lds[i + 1] = m0.y ? 0.f : -1e38f;
        bias_lds[i + 2] = m0.z ? 0.f : -1e38f;
        bias_lds[i + 3] = m0.w ? 0.f : -1e38f;
    }

    const int c0 = tid;
    const int r0 = c0 >> 3;
    const int kp0 = (c0 & 7) ^ ((((r0 >> 3) & 1) << 2) | (r0 & 3));
    const int vp0 = (c0 & 7) ^ (r0 & 7);
    const u16* kgp = Kb + ((size_t)b * TT) * CC + h * DD;
    const u16* vgp = Vt + ((size_t)(b * HH + h) * DD) * TT;

    const int rowA = ((l16 >> 2) << 3) | (l16 & 3);
    const int s0k  = (((l16 >> 2) & 1) << 2) | (l16 & 3);

    f32x4 o[2][4] = {};
    float lsum[2] = {};
    const float SC = 0.18033688011112042f;   // 0.125 * log2(e)

    GLDS(&kgp[(size_t)r0 * CC + kp0 * 8], &Ks[0][c0 * 8]);
    GLDS(&vgp[(size_t)r0 * TT + vp0 * 8], &Vs[0][c0 * 8]);
    asm volatile("s_waitcnt vmcnt(0) lgkmcnt(0)" ::: "memory");
    __builtin_amdgcn_s_barrier();
    __builtin_amdgcn_sched_barrier(0);

#pragma unroll 1
    for (int kt = 0; kt < TT; kt += 64) {
        const int cur = (kt >> 6) & 1;
        const u16* Kc = &Ks[cur][0];
        const u16* Vc = &Vs[cur][0];

        if (kt + 64 < TT) {
            const int nxt = cur ^ 1;
            GLDS(&kgp[(size_t)(kt + 64 + r0) * CC + kp0 * 8], &Ks[nxt][c0 * 8]);
            GLDS(&vgp[(size_t)r0 * TT + kt + 64 + vp0 * 8], &Vs[nxt][c0 * 8]);
        }

        const f32x4 bA = *(const f32x4*)&bias_lds[kt + quad * 8];
        const f32x4 bB = *(const f32x4*)&bias_lds[kt + quad * 8 + 4];
        const f32x4 bC = *(const f32x4*)&bias_lds[kt + 32 + quad * 8];
        const f32x4 bD = *(const f32x4*)&bias_lds[kt + 32 + quad * 8 + 4];

        f32x4 s2[2][4] = {};
        __builtin_amdgcn_s_setprio(1);
#pragma unroll
        for (int n = 0; n < 4; n++) {
            const int rowK = rowA + (n & 1) * 4 + (n >> 1) * 32;
#pragma unroll
            for (int ks = 0; ks < 2; ks++) {
                const int pos = ((ks << 2) + quad) ^ s0k;
                const bf16x8 kf = *(const bf16x8*)&Kc[rowK * 64 + pos * 8];
#pragma unroll
                for (int m = 0; m < 2; m++)
                    s2[m][n] = __builtin_amdgcn_mfma_f32_16x16x32_bf16(kf, qf[m][ks], s2[m][n], 0, 0, 0);
            }
        }
        __builtin_amdgcn_s_setprio(0);

#pragma unroll
        for (int ks = 0; ks < 2; ks++) {
            bf16x8 pf[2];
#pragma unroll
            for (int m = 0; m < 2; m++) {
                u32 pw[4];
#pragma unroll
                for (int nn = 0; nn < 2; nn++) {
                    const int n = 2 * ks + nn;
                    const f32x4 bv = (n == 0) ? bA : (n == 1) ? bB : (n == 2) ? bC : bD;
                    const float p0 = EXP2(fmaf(s2[m][n][0], SC, bv[0]));
                    const float p1 = EXP2(fmaf(s2[m][n][1], SC, bv[1]));
                    const float p2 = EXP2(fmaf(s2[m][n][2], SC, bv[2]));
                    const float p3 = EXP2(fmaf(s2[m][n][3], SC, bv[3]));
                    lsum[m] += (p0 + p1) + (p2 + p3);
                    pw[2 * nn]     = cvtpk(p0, p1);
                    pw[2 * nn + 1] = cvtpk(p2, p3);
                }
                const u32x4 t = { pw[0], pw[1], pw[2], pw[3] };
                pf[m] = __builtin_bit_cast(bf16x8, t);
            }
            __builtin_amdgcn_s_setprio(1);
#pragma unroll
            for (int dt = 0; dt < 4; dt++) {
                const int vrow = dt * 16 + l16;
                const int pos = ((ks << 2) + quad) ^ (vrow & 7);
                const bf16x8 vf = *(const bf16x8*)&Vc[vrow * 64 + pos * 8];
#pragma unroll
                for (int m = 0; m < 2; m++)
                    o[m][dt] = __builtin_amdgcn_mfma_f32_16x16x32_bf16(pf[m], vf, o[m][dt], 0, 0, 0);
            }
            __builtin_amdgcn_s_setprio(0);
        }

        asm volatile("s_waitcnt vmcnt(0)" ::: "memory");
        __builtin_amdgcn_sched_barrier(0);
        __builtin_amdgcn_s_barrier();
    }

#pragma unroll
    for (int m = 0; m < 2; m++) {
        lsum[m] += __shfl_xor(lsum[m], 16, 64);
        lsum[m] += __shfl_xor(lsum[m], 32, 64);
    }

#pragma unroll
    for (int m = 0; m < 2; m++) {
        float inv[4];
#pragma unroll
        for (int r = 0; r < 4; r++)
            inv[r] = 1.0f / __shfl(lsum[m], quad * 4 + r, 64);
#pragma unroll
        for (int dt = 0; dt < 4; dt++)
#pragma unroll
            for (int r = 0; r < 4; r++)
                Y[qb + (size_t)(m * 16 + quad * 4 + r) * CC + dt * 16 + l16] = f2bf(o[m][dt][r] * inv[r]);
    }
}

// ---------------------------------------------------------------------------
extern "C" void kernel_launch(void* const* d_in, const int* in_sizes, int n_in,
                              void* d_out, int out_size, void* d_ws, size_t ws_size,
                              hipStream_t stream) {
    const float* x    = (const float*)d_in[0];
    const int*   mask = (const int*)d_in[1];
    const float* Wq   = (const float*)d_in[2];
    const float* bq   = (const float*)d_in[3];
    const float* Wk   = (const float*)d_in[4];
    const float* bk   = (const float*)d_in[5];
    const float* Wv   = (const float*)d_in[6];
    const float* bv   = (const float*)d_in[7];
    const float* Wp   = (const float*)d_in[8];
    const float* bp   = (const float*)d_in[9];

    u16* ws = (u16*)d_ws;
    const size_t sz = (size_t)BB * TT * CC;     // 8,388,608 elems
    u16* Qb   = ws;              // Q; attn writes O here
    u16* Kbuf = ws + sz;         // K; reused for bf16 Wp after attn
    u16* Vtb  = ws + 2 * sz;     // V^T [B,H,D,T]   (ws total 48 MiB)

    u16* xb   = (u16*)d_out;     // squatters in d_out (dead by proj GEMM)
    u16* Wq16 = xb + sz;
    u16* Wk16 = Wq16 + (size_t)CC * CC;
    u16* Wv16 = Wk16 + (size_t)CC * CC;   // Wq16..Wv16 contiguous = W[3072][1024]

    static bool inited = false;
    if (!inited) {
        (void)hipFuncSetAttribute((const void*)gemm4p,
                                  hipFuncAttributeMaxDynamicSharedMemorySize, 131072);
        (void)hipFuncSetAttribute((const void*)gemmT<128, 128, 32, 64>,
                                  hipFuncAttributeMaxDynamicSharedMemorySize, 49152);
        inited = true;
    }

    const int W8 = CC * CC / 8;      // 131072

    wcvtA<<<5632, 256, 0, stream>>>(x, Wq, Wk, Wv, xb, Wq16, Wk16, Wv16);

    gemm4p<<<dim3(12, 32), 512, 131072, stream>>>(
        xb, Wq16, bq, bk, bv, Qb, Kbuf, Vtb);

    attn<<<dim3(TT / 256, HH, BB), 512, 0, stream>>>(Qb, Kbuf, Vtb, mask, Qb);

    wcvt<<<512, 256, 0, stream>>>(Wp, Kbuf, W8);   // Kbuf dead after attn

    gemmT<128, 128, 32, 64><<<dim3(8, 64), 512, 49152, stream>>>(
        Qb, Kbuf, bp, (float*)d_out);
}

// Round 9
// 278.023 us; speedup vs baseline: 1.0470x; 1.0308x over previous
//
#include <hip/hip_runtime.h>

// B=4, T=2048, C=1024, H=16, D=64. Device buffers f32 (mask int32).
// R19 = best-known GEMMs + attn KVBLK=128:
//   - QKV: R16's gemmT (256x128, BK=32, 3 LDS bufs, lead-2 counted vmcnt,
//     72KB -> 2 blocks/CU, grid 768 = 3 rounds/CU exactly). R17/R18's
//     256^2 1-block/CU reschedules all lost 20-25us to this -> family dead.
//   - proj: R18's gemmT <128,128,32,64> (512 blocks, 48KB -> 3/CU). R17 vs
//     R18 delta (~+4.5us) attributes to this; kept.
//   - attn: two 64-key subtiles per iteration (KVBLK=128). Barriers+drains
//     halve (32->16); prefetch lead doubles to ~2300cyc (>> HBM 900);
//     per-subtile compute byte-identical to the verified R12 geometry
//     (row+64 preserves sigma parity bits). LDS 40960->73728, still
//     2 blocks/CU (grid 512 is the occupancy cap).
// wcvtA/wcvt unchanged.

#define TT 2048
#define CC 1024
#define HH 16
#define DD 64
#define BB 4

typedef unsigned short u16;
typedef unsigned int u32;
typedef __attribute__((ext_vector_type(8))) short bf16x8;
typedef __attribute__((ext_vector_type(4))) float f32x4;
typedef __attribute__((ext_vector_type(4))) u32 u32x4;

#if __has_builtin(__builtin_amdgcn_exp2f)
#define EXP2(x) __builtin_amdgcn_exp2f(x)
#else
#define EXP2(x) __expf((x) * 0.6931471805599453f)
#endif

__device__ __forceinline__ u16 f2bf(float f) {
    u32 u = __builtin_bit_cast(u32, f);
    u += 0x7FFFu + ((u >> 16) & 1u);
    return (u16)(u >> 16);
}
__device__ __forceinline__ u32 pk2(float a, float b) {
    u32 ua = __builtin_bit_cast(u32, a); ua += 0x7FFFu + ((ua >> 16) & 1u);
    u32 ub = __builtin_bit_cast(u32, b); ub += 0x7FFFu + ((ub >> 16) & 1u);
    return __builtin_amdgcn_perm(ub, ua, 0x07060302);  // {hi16(ub), hi16(ua)}
}
__device__ __forceinline__ u32 cvtpk(float lo, float hi) {
    u32 r;
    asm("v_cvt_pk_bf16_f32 %0, %1, %2" : "=v"(r) : "v"(lo), "v"(hi));
    return r;
}

#define GLDS(g, l) __builtin_amdgcn_global_load_lds( \
    (const __attribute__((address_space(1))) void*)(g), \
    (__attribute__((address_space(3))) void*)(l), 16, 0, 0)

#define PH_SYNC() { __builtin_amdgcn_sched_barrier(0); \
                    __builtin_amdgcn_s_barrier(); \
                    __builtin_amdgcn_sched_barrier(0); }

// ---------------------------------------------------------------------------
__global__ __launch_bounds__(256) void wcvt(const float* __restrict__ s,
                                            u16* __restrict__ d, int n8) {
    const int i = blockIdx.x * 256 + threadIdx.x;
    if (i < n8) {
        const float4 f0 = ((const float4*)s)[2 * i];
        const float4 f1 = ((const float4*)s)[2 * i + 1];
        uint4 w;
        w.x = pk2(f0.x, f0.y); w.y = pk2(f0.z, f0.w);
        w.z = pk2(f1.x, f1.y); w.w = pk2(f1.z, f1.w);
        ((uint4*)d)[i] = w;
    }
}

// Fused f32->bf16: x (4096 blocks) + Wq/Wk/Wv (3x512 blocks).
__global__ __launch_bounds__(256) void wcvtA(const float* __restrict__ x,
                                             const float* __restrict__ Wq,
                                             const float* __restrict__ Wk,
                                             const float* __restrict__ Wv,
                                             u16* __restrict__ xb,
                                             u16* __restrict__ Wq16,
                                             u16* __restrict__ Wk16,
                                             u16* __restrict__ Wv16) {
    const int bid = blockIdx.x;
    const float* s; u16* d; int i;
    if (bid < 4096) {
        s = x; d = xb; i = bid * 256 + threadIdx.x;
    } else {
        const int t = bid - 4096;
        const int which = t >> 9, sub = t & 511;
        s = (which == 0) ? Wq : (which == 1) ? Wk : Wv;
        d = (which == 0) ? Wq16 : (which == 1) ? Wk16 : Wv16;
        i = sub * 256 + threadIdx.x;
    }
    const float4 f0 = ((const float4*)s)[2 * i];
    const float4 f1 = ((const float4*)s)[2 * i + 1];
    uint4 w;
    w.x = pk2(f0.x, f0.y); w.y = pk2(f0.z, f0.w);
    w.z = pk2(f1.x, f1.y); w.w = pk2(f1.z, f1.w);
    ((uint4*)d)[i] = w;
}

// ---------------------------------------------------------------------------
// Pipelined GEMM: out = A[8192,1024] @ W[N,1024]^T + bias.
// BM x BN tile, BK=32, 8 waves, 3 LDS buffers, stage lead 2, counted vmcnt
// (main-loop wait vmcnt(SPT): tile t+1 landed, t+2 in flight).
// MODE 0: QKV fused (bf16: Q rowmajor | K rowmajor | V^T [B,H,D,T]).
// MODE 1: proj (f32 out + bias).
// ---------------------------------------------------------------------------
template <int BM, int BN, int WM, int WN, int MODE>
__global__ __launch_bounds__(512, 4) void gemmT(const u16* __restrict__ Ag,
                                                const u16* __restrict__ Bg,
                                                const float* __restrict__ b0,
                                                const float* __restrict__ b1,
                                                const float* __restrict__ b2,
                                                u16* __restrict__ outQ,
                                                u16* __restrict__ outK,
                                                u16* __restrict__ outV,
                                                float* __restrict__ outF) {
    constexpr int NI = WM / 16, NJ = WN / 16;
    constexpr int WAVES_N = BN / WN;
    constexpr int BOFF = BM * 32;                 // B region start (elems)
    constexpr int BUFSZ = (BM + BN) * 32;
    constexpr int AG = BM / 128, BG = BN / 128;   // GLDS groups per tile
    constexpr int SPT = AG + BG;
    constexpr int NT = CC / 32;
    constexpr int NBX = (MODE == 0 ? 3072 : 1024) / BN;
    constexpr int NBY = 8192 / BM;

    extern __shared__ u16 lds[];
    const int tid  = threadIdx.x;
    const int wave = tid >> 6, lane = tid & 63;
    const int quad = lane >> 4, l16 = lane & 15;
    const int wr = wave / WAVES_N, wc = wave % WAVES_N;

    const int bid0 = blockIdx.y * NBX + blockIdx.x;
    const int chunk = (NBX * NBY) >> 3;
    const int bid  = (bid0 & 7) * chunk + (bid0 >> 3);
    const int bn = (bid % NBX) * BN, bm = (bid / NBX) * BM;

    u32 aOff[AG]; int aDst[AG];
#pragma unroll
    for (int g = 0; g < AG; g++) {
        const int c = g * 512 + tid;
        const int row = c >> 2;
        const int kc = (c & 3) ^ ((row >> 1) & 3);
        aOff[g] = (u32)(bm + row) * CC + kc * 8;
        aDst[g] = c * 8;
    }
    u32 bOff[BG]; int bDst[BG];
#pragma unroll
    for (int g = 0; g < BG; g++) {
        const int c = g * 512 + tid;
        const int row = c >> 2;
        const int kc = (c & 3) ^ ((row >> 1) & 3);
        bOff[g] = (u32)(bn + row) * CC + kc * 8;
        bDst[g] = BOFF + c * 8;
    }

    int aRd[NI], bRd[NJ];
#pragma unroll
    for (int i = 0; i < NI; i++) {
        const int row = wr * WM + i * 16 + l16;
        aRd[i] = row * 32 + (quad ^ ((row >> 1) & 3)) * 8;
    }
#pragma unroll
    for (int j = 0; j < NJ; j++) {
        const int row = wc * WN + j * 16 + l16;
        bRd[j] = BOFF + row * 32 + (quad ^ ((row >> 1) & 3)) * 8;
    }

    f32x4 acc[NI][NJ] = {};

#define STAGE_T(t)                                                        \
    {                                                                     \
        u16* dst = &lds[((t) % 3) * BUFSZ];                               \
        const int k0 = (t) * 32;                                          \
        _Pragma("unroll")                                                 \
        for (int g = 0; g < AG; g++)                                      \
            GLDS(&Ag[(size_t)aOff[g] + k0], &dst[aDst[g]]);               \
        _Pragma("unroll")                                                 \
        for (int g = 0; g < BG; g++)                                      \
            GLDS(&Bg[(size_t)bOff[g] + k0], &dst[bDst[g]]);               \
    }

#define COMPUTE_T(t)                                                      \
    {                                                                     \
        const u16* buf = &lds[((t) % 3) * BUFSZ];                         \
        bf16x8 af[NI], bfr[NJ];                                           \
        _Pragma("unroll")                                                 \
        for (int i = 0; i < NI; i++) af[i] = *(const bf16x8*)&buf[aRd[i]];\
        _Pragma("unroll")                                                 \
        for (int j = 0; j < NJ; j++) bfr[j] = *(const bf16x8*)&buf[bRd[j]];\
        __builtin_amdgcn_s_setprio(1);                                    \
        _Pragma("unroll")                                                 \
        for (int i = 0; i < NI; i++)                                      \
            _Pragma("unroll")                                             \
            for (int j = 0; j < NJ; j++)                                  \
                acc[i][j] = __builtin_amdgcn_mfma_f32_16x16x32_bf16(      \
                    af[i], bfr[j], acc[i][j], 0, 0, 0);                   \
        __builtin_amdgcn_s_setprio(0);                                    \
    }

#define WAIT_MAIN()                                                       \
    if constexpr (SPT == 2) asm volatile("s_waitcnt vmcnt(2)" ::: "memory"); \
    else if constexpr (SPT == 3) asm volatile("s_waitcnt vmcnt(3)" ::: "memory"); \
    else asm volatile("s_waitcnt vmcnt(4)" ::: "memory");

    STAGE_T(0); STAGE_T(1);
    WAIT_MAIN();
    PH_SYNC();

#pragma unroll 1
    for (int t = 0; t < NT - 2; t++) {
        STAGE_T(t + 2);
        COMPUTE_T(t);
        WAIT_MAIN();
        PH_SYNC();
    }
    COMPUTE_T(NT - 2);
    asm volatile("s_waitcnt vmcnt(0)" ::: "memory");
    PH_SYNC();
    COMPUTE_T(NT - 1);

#undef STAGE_T
#undef COMPUTE_T
#undef WAIT_MAIN

    // ---- epilogue ----
    if (MODE == 1) {
#pragma unroll
        for (int j = 0; j < NJ; j++) {
            const int col = bn + wc * WN + j * 16 + l16;
            const float bv = b0[col];
#pragma unroll
            for (int i = 0; i < NI; i++) {
                const int row0 = bm + wr * WM + i * 16 + quad * 4;
#pragma unroll
                for (int r = 0; r < 4; r++)
                    outF[(size_t)(row0 + r) * CC + col] = acc[i][j][r] + bv;
            }
        }
    } else {
        const int mid = bn >> 10;   // 0=Q,1=K,2=V (block-uniform; BN | 1024)
        const float* bias = (mid == 0) ? b0 : (mid == 1) ? b1 : b2;
#pragma unroll
        for (int j = 0; j < NJ; j++) {
            const int col  = bn + wc * WN + j * 16 + l16;
            const int colL = col & (CC - 1);
            const float bv = bias[colL];
#pragma unroll
            for (int i = 0; i < NI; i++) {
                const int row0 = bm + wr * WM + i * 16 + quad * 4;
                if (mid < 2) {
                    u16* out = mid ? outK : outQ;
#pragma unroll
                    for (int r = 0; r < 4; r++)
                        out[(size_t)(row0 + r) * CC + colL] = f2bf(acc[i][j][r] + bv);
                } else {
                    const int hh = colL >> 6, dch = colL & 63;
                    const int bb = row0 >> 11, t0 = row0 & (TT - 1);
                    const size_t idx = (((size_t)bb * HH + hh) * DD + dch) * TT + t0;
                    uint2 w;
                    w.x = pk2(acc[i][j][0] + bv, acc[i][j][1] + bv);
                    w.y = pk2(acc[i][j][2] + bv, acc[i][j][3] + bv);
                    *(uint2*)&outV[idx] = w;
                }
            }
        }
    }
}

// ---------------------------------------------------------------------------
// Flash attention, KVBLK=128 (two 64-key subtiles per iteration).
// Block = (qt,h,b): 256 q-rows, 8 waves x 32 rows. Swapped QK^T, in-register
// P, ks-split softmax/PV (all per-subtile geometry identical to R12).
// 16 iterations: prefetch 4 GLDS at top (lead ~2300cyc), ONE vmcnt(0)+
// barrier at bottom (was 32 barriers at KVBLK=64).
// ---------------------------------------------------------------------------
__global__ __launch_bounds__(512) void attn(const u16* __restrict__ Q,
                                            const u16* __restrict__ Kb,
                                            const u16* __restrict__ Vt,
                                            const int* __restrict__ mask,
                                            u16* __restrict__ Y) {
    const int b = blockIdx.z, h = blockIdx.y, qt = blockIdx.x;
    const int tid  = threadIdx.x;
    const int wave = tid >> 6, lane = tid & 63;
    const int quad = lane >> 4, l16 = lane & 15;
    const int qrow0 = qt * 256 + wave * 32;

    __shared__ u16 Ks[2][2][64 * 64];           // [buf][subtile][key][dim]
    __shared__ u16 Vs[2][2][64 * 64];           // [buf][subtile][d][key]
    __shared__ __align__(16) float bias_lds[TT];  // 0 or -1e38 per key

    const size_t qb = ((size_t)b * TT + qrow0) * CC + h * DD;

    bf16x8 qf[2][2];
#pragma unroll
    for (int m = 0; m < 2; m++)
#pragma unroll
        for (int ks = 0; ks < 2; ks++)
            qf[m][ks] = *(const bf16x8*)&Q[qb + (size_t)(m * 16 + l16) * CC + ks * 32 + quad * 8];

    {
        const int i = tid * 4;
        const int4 m0 = *(const int4*)&mask[b * TT + i];
        bias_lds[i + 0] = m0.x ? 0.f : -1e38f;
        bias_lds[i + 1] = m0.y ? 0.f : -1e38f;
        bias_lds[i + 2] = m0.z ? 0.f : -1e38f;
        bias_lds[i + 3] = m0.w ? 0.f : -1e38f;
    }

    const int c0 = tid;
    const int r0 = c0 >> 3;
    const int kp0 = (c0 & 7) ^ ((((r0 >> 3) & 1) << 2) | (r0 & 3));
    const int vp0 = (c0 & 7) ^ (r0 & 7);
    const u16* kgp = Kb + ((size_t)b * TT) * CC + h * DD;
    const u16* vgp = Vt + ((size_t)(b * HH + h) * DD) * TT;

    const int rowA = ((l16 >> 2) << 3) | (l16 & 3);
    const int s0k  = (((l16 >> 2) & 1) << 2) | (l16 & 3);

    f32x4 o[2][4] = {};
    float lsum[2] = {};
    const float SC = 0.18033688011112042f;   // 0.125 * log2(e)

    // prologue: stage both subtiles of tile 0 into buffer 0
    GLDS(&kgp[(size_t)r0 * CC + kp0 * 8],        &Ks[0][0][c0 * 8]);
    GLDS(&kgp[(size_t)(64 + r0) * CC + kp0 * 8], &Ks[0][1][c0 * 8]);
    GLDS(&vgp[(size_t)r0 * TT + vp0 * 8],        &Vs[0][0][c0 * 8]);
    GLDS(&vgp[(size_t)r0 * TT + 64 + vp0 * 8],   &Vs[0][1][c0 * 8]);
    asm volatile("s_waitcnt vmcnt(0) lgkmcnt(0)" ::: "memory");
    __builtin_amdgcn_s_barrier();
    __builtin_amdgcn_sched_barrier(0);

#pragma unroll 1
    for (int kt = 0; kt < TT; kt += 128) {
        const int cur = (kt >> 7) & 1;

        // prefetch next 128-key tile (4 GLDS); in flight across 2 subtiles
        if (kt + 128 < TT) {
            const int nxt = cur ^ 1;
            const int kt2 = kt + 128;
            GLDS(&kgp[(size_t)(kt2 + r0) * CC + kp0 * 8],      &Ks[nxt][0][c0 * 8]);
            GLDS(&kgp[(size_t)(kt2 + 64 + r0) * CC + kp0 * 8], &Ks[nxt][1][c0 * 8]);
            GLDS(&vgp[(size_t)r0 * TT + kt2 + vp0 * 8],        &Vs[nxt][0][c0 * 8]);
            GLDS(&vgp[(size_t)r0 * TT + kt2 + 64 + vp0 * 8],   &Vs[nxt][1][c0 * 8]);
        }

#pragma unroll
        for (int sx = 0; sx < 2; sx++) {
            const u16* Kc = &Ks[cur][sx][0];
            const u16* Vc = &Vs[cur][sx][0];
            const int kb = kt + sx * 64;

            const f32x4 bA = *(const f32x4*)&bias_lds[kb + quad * 8];
            const f32x4 bB = *(const f32x4*)&bias_lds[kb + quad * 8 + 4];
            const f32x4 bC = *(const f32x4*)&bias_lds[kb + 32 + quad * 8];
            const f32x4 bD = *(const f32x4*)&bias_lds[kb + 32 + quad * 8 + 4];

            f32x4 s2[2][4] = {};
            __builtin_amdgcn_s_setprio(1);
#pragma unroll
            for (int n = 0; n < 4; n++) {
                const int rowK = rowA + (n & 1) * 4 + (n >> 1) * 32;
#pragma unroll
                for (int ks = 0; ks < 2; ks++) {
                    const int pos = ((ks << 2) + quad) ^ s0k;
                    const bf16x8 kf = *(const bf16x8*)&Kc[rowK * 64 + pos * 8];
#pragma unroll
                    for (int m = 0; m < 2; m++)
                        s2[m][n] = __builtin_amdgcn_mfma_f32_16x16x32_bf16(kf, qf[m][ks], s2[m][n], 0, 0, 0);
                }
            }
            __builtin_amdgcn_s_setprio(0);

#pragma unroll
            for (int ks = 0; ks < 2; ks++) {
                bf16x8 pf[2];
#pragma unroll
                for (int m = 0; m < 2; m++) {
                    u32 pw[4];
#pragma unroll
                    for (int nn = 0; nn < 2; nn++) {
                        const int n = 2 * ks + nn;
                        const f32x4 bv = (n == 0) ? bA : (n == 1) ? bB : (n == 2) ? bC : bD;
                        const float p0 = EXP2(fmaf(s2[m][n][0], SC, bv[0]));
                        const float p1 = EXP2(fmaf(s2[m][n][1], SC, bv[1]));
                        const float p2 = EXP2(fmaf(s2[m][n][2], SC, bv[2]));
                        const float p3 = EXP2(fmaf(s2[m][n][3], SC, bv[3]));
                        lsum[m] += (p0 + p1) + (p2 + p3);
                        pw[2 * nn]     = cvtpk(p0, p1);
                        pw[2 * nn + 1] = cvtpk(p2, p3);
                    }
                    const u32x4 t = { pw[0], pw[1], pw[2], pw[3] };
                    pf[m] = __builtin_bit_cast(bf16x8, t);
                }
                __builtin_amdgcn_s_setprio(1);
#pragma unroll
                for (int dt = 0; dt < 4; dt++) {
                    const int vrow = dt * 16 + l16;
                    const int pos = ((ks << 2) + quad) ^ (vrow & 7);
                    const bf16x8 vf = *(const bf16x8*)&Vc[vrow * 64 + pos * 8];
#pragma unroll
                    for (int m = 0; m < 2; m++)
                        o[m][dt] = __builtin_amdgcn_mfma_f32_16x16x32_bf16(pf[m], vf, o[m][dt], 0, 0, 0);
                }
                __builtin_amdgcn_s_setprio(0);
            }
        }

        // one drain + barrier per 128 keys; prefetch is ~2 subtiles old
        asm volatile("s_waitcnt vmcnt(0)" ::: "memory");
        __builtin_amdgcn_sched_barrier(0);
        __builtin_amdgcn_s_barrier();
    }

#pragma unroll
    for (int m = 0; m < 2; m++) {
        lsum[m] += __shfl_xor(lsum[m], 16, 64);
        lsum[m] += __shfl_xor(lsum[m], 32, 64);
    }

#pragma unroll
    for (int m = 0; m < 2; m++) {
        float inv[4];
#pragma unroll
        for (int r = 0; r < 4; r++)
            inv[r] = 1.0f / __shfl(lsum[m], quad * 4 + r, 64);
#pragma unroll
        for (int dt = 0; dt < 4; dt++)
#pragma unroll
            for (int r = 0; r < 4; r++)
                Y[qb + (size_t)(m * 16 + quad * 4 + r) * CC + dt * 16 + l16] = f2bf(o[m][dt][r] * inv[r]);
    }
}

// ---------------------------------------------------------------------------
extern "C" void kernel_launch(void* const* d_in, const int* in_sizes, int n_in,
                              void* d_out, int out_size, void* d_ws, size_t ws_size,
                              hipStream_t stream) {
    const float* x    = (const float*)d_in[0];
    const int*   mask = (const int*)d_in[1];
    const float* Wq   = (const float*)d_in[2];
    const float* bq   = (const float*)d_in[3];
    const float* Wk   = (const float*)d_in[4];
    const float* bk   = (const float*)d_in[5];
    const float* Wv   = (const float*)d_in[6];
    const float* bv   = (const float*)d_in[7];
    const float* Wp   = (const float*)d_in[8];
    const float* bp   = (const float*)d_in[9];

    u16* ws = (u16*)d_ws;
    const size_t sz = (size_t)BB * TT * CC;     // 8,388,608 elems
    u16* Qb   = ws;              // Q; attn writes O here
    u16* Kbuf = ws + sz;         // K; reused for bf16 Wp after attn
    u16* Vtb  = ws + 2 * sz;     // V^T [B,H,D,T]   (ws total 48 MiB)

    u16* xb   = (u16*)d_out;     // squatters in d_out (dead by proj GEMM)
    u16* Wq16 = xb + sz;
    u16* Wk16 = Wq16 + (size_t)CC * CC;
    u16* Wv16 = Wk16 + (size_t)CC * CC;   // Wq16..Wv16 contiguous = W[3072][1024]

    static bool inited = false;
    if (!inited) {
        (void)hipFuncSetAttribute((const void*)gemmT<256, 128, 64, 64, 0>,
                                  hipFuncAttributeMaxDynamicSharedMemorySize, 73728);
        (void)hipFuncSetAttribute((const void*)gemmT<128, 128, 32, 64, 1>,
                                  hipFuncAttributeMaxDynamicSharedMemorySize, 49152);
        inited = true;
    }

    const int W8 = CC * CC / 8;      // 131072

    wcvtA<<<5632, 256, 0, stream>>>(x, Wq, Wk, Wv, xb, Wq16, Wk16, Wv16);

    gemmT<256, 128, 64, 64, 0><<<dim3(24, 32), 512, 73728, stream>>>(
        xb, Wq16, bq, bk, bv, Qb, Kbuf, Vtb, nullptr);

    attn<<<dim3(TT / 256, HH, BB), 512, 0, stream>>>(Qb, Kbuf, Vtb, mask, Qb);

    wcvt<<<512, 256, 0, stream>>>(Wp, Kbuf, W8);   // Kbuf dead after attn

    gemmT<128, 128, 32, 64, 1><<<dim3(8, 64), 512, 49152, stream>>>(
        Qb, Kbuf, bp, nullptr, nullptr, nullptr, nullptr, nullptr, (float*)d_out);
}

// Round 10
// 275.334 us; speedup vs baseline: 1.0572x; 1.0098x over previous
//
#include <hip/hip_runtime.h>

// B=4, T=2048, C=1024, H=16, D=64. Device buffers f32 (mask int32).
// R20 = measured-best assembly (no new structures):
//   - attn: byte-identical revert to R12 (40960 LDS -> 2 blocks/CU, 92us,
//     MfmaUtil 31, conflicts 0). R19's KVBLK=128 cost occupancy 35->21%
//     (73728 LDS -> 1 block/CU) and regressed 17us: attn's engine is
//     cross-block TLP, not barrier amortization.
//   - QKV: R16 gemmT<256,128,64,64,0> (BK=32, 3 bufs, lead-2 counted vmcnt,
//     72KB -> 2 blocks/CU, grid 768 = exactly 3 rounds).
//   - proj: R18 gemmT<128,128,32,64,1> (512 blocks, 48KB -> 3/CU; worth
//     ~5us vs R16's 256-block proj per R19 residual analysis).
// R19 residual (non-attn) = 169.3us measured; predicted total ~261.

#define TT 2048
#define CC 1024
#define HH 16
#define DD 64
#define BB 4

typedef unsigned short u16;
typedef unsigned int u32;
typedef __attribute__((ext_vector_type(8))) short bf16x8;
typedef __attribute__((ext_vector_type(4))) float f32x4;
typedef __attribute__((ext_vector_type(4))) u32 u32x4;

#if __has_builtin(__builtin_amdgcn_exp2f)
#define EXP2(x) __builtin_amdgcn_exp2f(x)
#else
#define EXP2(x) __expf((x) * 0.6931471805599453f)
#endif

__device__ __forceinline__ u16 f2bf(float f) {
    u32 u = __builtin_bit_cast(u32, f);
    u += 0x7FFFu + ((u >> 16) & 1u);
    return (u16)(u >> 16);
}
__device__ __forceinline__ u32 pk2(float a, float b) {
    u32 ua = __builtin_bit_cast(u32, a); ua += 0x7FFFu + ((ua >> 16) & 1u);
    u32 ub = __builtin_bit_cast(u32, b); ub += 0x7FFFu + ((ub >> 16) & 1u);
    return __builtin_amdgcn_perm(ub, ua, 0x07060302);  // {hi16(ub), hi16(ua)}
}
__device__ __forceinline__ u32 cvtpk(float lo, float hi) {
    u32 r;
    asm("v_cvt_pk_bf16_f32 %0, %1, %2" : "=v"(r) : "v"(lo), "v"(hi));
    return r;
}

#define GLDS(g, l) __builtin_amdgcn_global_load_lds( \
    (const __attribute__((address_space(1))) void*)(g), \
    (__attribute__((address_space(3))) void*)(l), 16, 0, 0)

#define PH_SYNC() { __builtin_amdgcn_sched_barrier(0); \
                    __builtin_amdgcn_s_barrier(); \
                    __builtin_amdgcn_sched_barrier(0); }

// ---------------------------------------------------------------------------
__global__ __launch_bounds__(256) void wcvt(const float* __restrict__ s,
                                            u16* __restrict__ d, int n8) {
    const int i = blockIdx.x * 256 + threadIdx.x;
    if (i < n8) {
        const float4 f0 = ((const float4*)s)[2 * i];
        const float4 f1 = ((const float4*)s)[2 * i + 1];
        uint4 w;
        w.x = pk2(f0.x, f0.y); w.y = pk2(f0.z, f0.w);
        w.z = pk2(f1.x, f1.y); w.w = pk2(f1.z, f1.w);
        ((uint4*)d)[i] = w;
    }
}

// Fused f32->bf16: x (4096 blocks) + Wq/Wk/Wv (3x512 blocks).
__global__ __launch_bounds__(256) void wcvtA(const float* __restrict__ x,
                                             const float* __restrict__ Wq,
                                             const float* __restrict__ Wk,
                                             const float* __restrict__ Wv,
                                             u16* __restrict__ xb,
                                             u16* __restrict__ Wq16,
                                             u16* __restrict__ Wk16,
                                             u16* __restrict__ Wv16) {
    const int bid = blockIdx.x;
    const float* s; u16* d; int i;
    if (bid < 4096) {
        s = x; d = xb; i = bid * 256 + threadIdx.x;
    } else {
        const int t = bid - 4096;
        const int which = t >> 9, sub = t & 511;
        s = (which == 0) ? Wq : (which == 1) ? Wk : Wv;
        d = (which == 0) ? Wq16 : (which == 1) ? Wk16 : Wv16;
        i = sub * 256 + threadIdx.x;
    }
    const float4 f0 = ((const float4*)s)[2 * i];
    const float4 f1 = ((const float4*)s)[2 * i + 1];
    uint4 w;
    w.x = pk2(f0.x, f0.y); w.y = pk2(f0.z, f0.w);
    w.z = pk2(f1.x, f1.y); w.w = pk2(f1.z, f1.w);
    ((uint4*)d)[i] = w;
}

// ---------------------------------------------------------------------------
// Pipelined GEMM: out = A[8192,1024] @ W[N,1024]^T + bias.
// BM x BN tile, BK=32, 8 waves, 3 LDS buffers, stage lead 2, counted vmcnt
// (main-loop wait vmcnt(SPT): tile t+1 landed, t+2 in flight).
// MODE 0: QKV fused (bf16: Q rowmajor | K rowmajor | V^T [B,H,D,T]).
// MODE 1: proj (f32 out + bias).
// ---------------------------------------------------------------------------
template <int BM, int BN, int WM, int WN, int MODE>
__global__ __launch_bounds__(512, 4) void gemmT(const u16* __restrict__ Ag,
                                                const u16* __restrict__ Bg,
                                                const float* __restrict__ b0,
                                                const float* __restrict__ b1,
                                                const float* __restrict__ b2,
                                                u16* __restrict__ outQ,
                                                u16* __restrict__ outK,
                                                u16* __restrict__ outV,
                                                float* __restrict__ outF) {
    constexpr int NI = WM / 16, NJ = WN / 16;
    constexpr int WAVES_N = BN / WN;
    constexpr int BOFF = BM * 32;                 // B region start (elems)
    constexpr int BUFSZ = (BM + BN) * 32;
    constexpr int AG = BM / 128, BG = BN / 128;   // GLDS groups per tile
    constexpr int SPT = AG + BG;
    constexpr int NT = CC / 32;
    constexpr int NBX = (MODE == 0 ? 3072 : 1024) / BN;
    constexpr int NBY = 8192 / BM;

    extern __shared__ u16 lds[];
    const int tid  = threadIdx.x;
    const int wave = tid >> 6, lane = tid & 63;
    const int quad = lane >> 4, l16 = lane & 15;
    const int wr = wave / WAVES_N, wc = wave % WAVES_N;

    const int bid0 = blockIdx.y * NBX + blockIdx.x;
    const int chunk = (NBX * NBY) >> 3;
    const int bid  = (bid0 & 7) * chunk + (bid0 >> 3);
    const int bn = (bid % NBX) * BN, bm = (bid / NBX) * BM;

    u32 aOff[AG]; int aDst[AG];
#pragma unroll
    for (int g = 0; g < AG; g++) {
        const int c = g * 512 + tid;
        const int row = c >> 2;
        const int kc = (c & 3) ^ ((row >> 1) & 3);
        aOff[g] = (u32)(bm + row) * CC + kc * 8;
        aDst[g] = c * 8;
    }
    u32 bOff[BG]; int bDst[BG];
#pragma unroll
    for (int g = 0; g < BG; g++) {
        const int c = g * 512 + tid;
        const int row = c >> 2;
        const int kc = (c & 3) ^ ((row >> 1) & 3);
        bOff[g] = (u32)(bn + row) * CC + kc * 8;
        bDst[g] = BOFF + c * 8;
    }

    int aRd[NI], bRd[NJ];
#pragma unroll
    for (int i = 0; i < NI; i++) {
        const int row = wr * WM + i * 16 + l16;
        aRd[i] = row * 32 + (quad ^ ((row >> 1) & 3)) * 8;
    }
#pragma unroll
    for (int j = 0; j < NJ; j++) {
        const int row = wc * WN + j * 16 + l16;
        bRd[j] = BOFF + row * 32 + (quad ^ ((row >> 1) & 3)) * 8;
    }

    f32x4 acc[NI][NJ] = {};

#define STAGE_T(t)                                                        \
    {                                                                     \
        u16* dst = &lds[((t) % 3) * BUFSZ];                               \
        const int k0 = (t) * 32;                                          \
        _Pragma("unroll")                                                 \
        for (int g = 0; g < AG; g++)                                      \
            GLDS(&Ag[(size_t)aOff[g] + k0], &dst[aDst[g]]);               \
        _Pragma("unroll")                                                 \
        for (int g = 0; g < BG; g++)                                      \
            GLDS(&Bg[(size_t)bOff[g] + k0], &dst[bDst[g]]);               \
    }

#define COMPUTE_T(t)                                                      \
    {                                                                     \
        const u16* buf = &lds[((t) % 3) * BUFSZ];                         \
        bf16x8 af[NI], bfr[NJ];                                           \
        _Pragma("unroll")                                                 \
        for (int i = 0; i < NI; i++) af[i] = *(const bf16x8*)&buf[aRd[i]];\
        _Pragma("unroll")                                                 \
        for (int j = 0; j < NJ; j++) bfr[j] = *(const bf16x8*)&buf[bRd[j]];\
        __builtin_amdgcn_s_setprio(1);                                    \
        _Pragma("unroll")                                                 \
        for (int i = 0; i < NI; i++)                                      \
            _Pragma("unroll")                                             \
            for (int j = 0; j < NJ; j++)                                  \
                acc[i][j] = __builtin_amdgcn_mfma_f32_16x16x32_bf16(      \
                    af[i], bfr[j], acc[i][j], 0, 0, 0);                   \
        __builtin_amdgcn_s_setprio(0);                                    \
    }

#define WAIT_MAIN()                                                       \
    if constexpr (SPT == 2) asm volatile("s_waitcnt vmcnt(2)" ::: "memory"); \
    else if constexpr (SPT == 3) asm volatile("s_waitcnt vmcnt(3)" ::: "memory"); \
    else asm volatile("s_waitcnt vmcnt(4)" ::: "memory");

    STAGE_T(0); STAGE_T(1);
    WAIT_MAIN();
    PH_SYNC();

#pragma unroll 1
    for (int t = 0; t < NT - 2; t++) {
        STAGE_T(t + 2);
        COMPUTE_T(t);
        WAIT_MAIN();
        PH_SYNC();
    }
    COMPUTE_T(NT - 2);
    asm volatile("s_waitcnt vmcnt(0)" ::: "memory");
    PH_SYNC();
    COMPUTE_T(NT - 1);

#undef STAGE_T
#undef COMPUTE_T
#undef WAIT_MAIN

    // ---- epilogue ----
    if (MODE == 1) {
#pragma unroll
        for (int j = 0; j < NJ; j++) {
            const int col = bn + wc * WN + j * 16 + l16;
            const float bv = b0[col];
#pragma unroll
            for (int i = 0; i < NI; i++) {
                const int row0 = bm + wr * WM + i * 16 + quad * 4;
#pragma unroll
                for (int r = 0; r < 4; r++)
                    outF[(size_t)(row0 + r) * CC + col] = acc[i][j][r] + bv;
            }
        }
    } else {
        const int mid = bn >> 10;   // 0=Q,1=K,2=V (block-uniform; BN | 1024)
        const float* bias = (mid == 0) ? b0 : (mid == 1) ? b1 : b2;
#pragma unroll
        for (int j = 0; j < NJ; j++) {
            const int col  = bn + wc * WN + j * 16 + l16;
            const int colL = col & (CC - 1);
            const float bv = bias[colL];
#pragma unroll
            for (int i = 0; i < NI; i++) {
                const int row0 = bm + wr * WM + i * 16 + quad * 4;
                if (mid < 2) {
                    u16* out = mid ? outK : outQ;
#pragma unroll
                    for (int r = 0; r < 4; r++)
                        out[(size_t)(row0 + r) * CC + colL] = f2bf(acc[i][j][r] + bv);
                } else {
                    const int hh = colL >> 6, dch = colL & 63;
                    const int bb = row0 >> 11, t0 = row0 & (TT - 1);
                    const size_t idx = (((size_t)bb * HH + hh) * DD + dch) * TT + t0;
                    uint2 w;
                    w.x = pk2(acc[i][j][0] + bv, acc[i][j][1] + bv);
                    w.y = pk2(acc[i][j][2] + bv, acc[i][j][3] + bv);
                    *(uint2*)&outV[idx] = w;
                }
            }
        }
    }
}

// ---------------------------------------------------------------------------
// Flash attention (byte-identical to R12). Block = (qt,h,b): 256 q-rows,
// 8 waves x 32 rows. Swapped QK^T, in-register P, ks-split softmax/PV,
// double-buffered GLDS, single raw barrier per tile. LDS 40960 -> 2 blk/CU.
// ---------------------------------------------------------------------------
__global__ __launch_bounds__(512) void attn(const u16* __restrict__ Q,
                                            const u16* __restrict__ Kb,
                                            const u16* __restrict__ Vt,
                                            const int* __restrict__ mask,
                                            u16* __restrict__ Y) {
    const int b = blockIdx.z, h = blockIdx.y, qt = blockIdx.x;
    const int tid  = threadIdx.x;
    const int wave = tid >> 6, lane = tid & 63;
    const int quad = lane >> 4, l16 = lane & 15;
    const int qrow0 = qt * 256 + wave * 32;

    __shared__ u16 Ks[2][64 * 64];              // [key][dim]
    __shared__ u16 Vs[2][64 * 64];              // [d][key]
    __shared__ __align__(16) float bias_lds[TT];  // 0 or -1e38 per key

    const size_t qb = ((size_t)b * TT + qrow0) * CC + h * DD;

    bf16x8 qf[2][2];
#pragma unroll
    for (int m = 0; m < 2; m++)
#pragma unroll
        for (int ks = 0; ks < 2; ks++)
            qf[m][ks] = *(const bf16x8*)&Q[qb + (size_t)(m * 16 + l16) * CC + ks * 32 + quad * 8];

    {
        const int i = tid * 4;
        const int4 m0 = *(const int4*)&mask[b * TT + i];
        bias_lds[i + 0] = m0.x ? 0.f : -1e38f;
        bias_lds[i + 1] = m0.y ? 0.f : -1e38f;
        bias_lds[i + 2] = m0.z ? 0.f : -1e38f;
        bias_lds[i + 3] = m0.w ? 0.f : -1e38f;
    }

    const int c0 = tid;
    const int r0 = c0 >> 3;
    const int kp0 = (c0 & 7) ^ ((((r0 >> 3) & 1) << 2) | (r0 & 3));
    const int vp0 = (c0 & 7) ^ (r0 & 7);
    const u16* kgp = Kb + ((size_t)b * TT) * CC + h * DD;
    const u16* vgp = Vt + ((size_t)(b * HH + h) * DD) * TT;

    const int rowA = ((l16 >> 2) << 3) | (l16 & 3);
    const int s0k  = (((l16 >> 2) & 1) << 2) | (l16 & 3);

    f32x4 o[2][4] = {};
    float lsum[2] = {};
    const float SC = 0.18033688011112042f;   // 0.125 * log2(e)

    GLDS(&kgp[(size_t)r0 * CC + kp0 * 8], &Ks[0][c0 * 8]);
    GLDS(&vgp[(size_t)r0 * TT + vp0 * 8], &Vs[0][c0 * 8]);
    asm volatile("s_waitcnt vmcnt(0) lgkmcnt(0)" ::: "memory");
    __builtin_amdgcn_s_barrier();
    __builtin_amdgcn_sched_barrier(0);

#pragma unroll 1
    for (int kt = 0; kt < TT; kt += 64) {
        const int cur = (kt >> 6) & 1;
        const u16* Kc = &Ks[cur][0];
        const u16* Vc = &Vs[cur][0];

        if (kt + 64 < TT) {
            const int nxt = cur ^ 1;
            GLDS(&kgp[(size_t)(kt + 64 + r0) * CC + kp0 * 8], &Ks[nxt][c0 * 8]);
            GLDS(&vgp[(size_t)r0 * TT + kt + 64 + vp0 * 8], &Vs[nxt][c0 * 8]);
        }

        const f32x4 bA = *(const f32x4*)&bias_lds[kt + quad * 8];
        const f32x4 bB = *(const f32x4*)&bias_lds[kt + quad * 8 + 4];
        const f32x4 bC = *(const f32x4*)&bias_lds[kt + 32 + quad * 8];
        const f32x4 bD = *(const f32x4*)&bias_lds[kt + 32 + quad * 8 + 4];

        f32x4 s2[2][4] = {};
        __builtin_amdgcn_s_setprio(1);
#pragma unroll
        for (int n = 0; n < 4; n++) {
            const int rowK = rowA + (n & 1) * 4 + (n >> 1) * 32;
#pragma unroll
            for (int ks = 0; ks < 2; ks++) {
                const int pos = ((ks << 2) + quad) ^ s0k;
                const bf16x8 kf = *(const bf16x8*)&Kc[rowK * 64 + pos * 8];
#pragma unroll
                for (int m = 0; m < 2; m++)
                    s2[m][n] = __builtin_amdgcn_mfma_f32_16x16x32_bf16(kf, qf[m][ks], s2[m][n], 0, 0, 0);
            }
        }
        __builtin_amdgcn_s_setprio(0);

#pragma unroll
        for (int ks = 0; ks < 2; ks++) {
            bf16x8 pf[2];
#pragma unroll
            for (int m = 0; m < 2; m++) {
                u32 pw[4];
#pragma unroll
                for (int nn = 0; nn < 2; nn++) {
                    const int n = 2 * ks + nn;
                    const f32x4 bv = (n == 0) ? bA : (n == 1) ? bB : (n == 2) ? bC : bD;
                    const float p0 = EXP2(fmaf(s2[m][n][0], SC, bv[0]));
                    const float p1 = EXP2(fmaf(s2[m][n][1], SC, bv[1]));
                    const float p2 = EXP2(fmaf(s2[m][n][2], SC, bv[2]));
                    const float p3 = EXP2(fmaf(s2[m][n][3], SC, bv[3]));
                    lsum[m] += (p0 + p1) + (p2 + p3);
                    pw[2 * nn]     = cvtpk(p0, p1);
                    pw[2 * nn + 1] = cvtpk(p2, p3);
                }
                const u32x4 t = { pw[0], pw[1], pw[2], pw[3] };
                pf[m] = __builtin_bit_cast(bf16x8, t);
            }
            __builtin_amdgcn_s_setprio(1);
#pragma unroll
            for (int dt = 0; dt < 4; dt++) {
                const int vrow = dt * 16 + l16;
                const int pos = ((ks << 2) + quad) ^ (vrow & 7);
                const bf16x8 vf = *(const bf16x8*)&Vc[vrow * 64 + pos * 8];
#pragma unroll
                for (int m = 0; m < 2; m++)
                    o[m][dt] = __builtin_amdgcn_mfma_f32_16x16x32_bf16(pf[m], vf, o[m][dt], 0, 0, 0);
            }
            __builtin_amdgcn_s_setprio(0);
        }

        asm volatile("s_waitcnt vmcnt(0)" ::: "memory");
        __builtin_amdgcn_sched_barrier(0);
        __builtin_amdgcn_s_barrier();
    }

#pragma unroll
    for (int m = 0; m < 2; m++) {
        lsum[m] += __shfl_xor(lsum[m], 16, 64);
        lsum[m] += __shfl_xor(lsum[m], 32, 64);
    }

#pragma unroll
    for (int m = 0; m < 2; m++) {
        float inv[4];
#pragma unroll
        for (int r = 0; r < 4; r++)
            inv[r] = 1.0f / __shfl(lsum[m], quad * 4 + r, 64);
#pragma unroll
        for (int dt = 0; dt < 4; dt++)
#pragma unroll
            for (int r = 0; r < 4; r++)
                Y[qb + (size_t)(m * 16 + quad * 4 + r) * CC + dt * 16 + l16] = f2bf(o[m][dt][r] * inv[r]);
    }
}

// ---------------------------------------------------------------------------
extern "C" void kernel_launch(void* const* d_in, const int* in_sizes, int n_in,
                              void* d_out, int out_size, void* d_ws, size_t ws_size,
                              hipStream_t stream) {
    const float* x    = (const float*)d_in[0];
    const int*   mask = (const int*)d_in[1];
    const float* Wq   = (const float*)d_in[2];
    const float* bq   = (const float*)d_in[3];
    const float* Wk   = (const float*)d_in[4];
    const float* bk   = (const float*)d_in[5];
    const float* Wv   = (const float*)d_in[6];
    const float* bv   = (const float*)d_in[7];
    const float* Wp   = (const float*)d_in[8];
    const float* bp   = (const float*)d_in[9];

    u16* ws = (u16*)d_ws;
    const size_t sz = (size_t)BB * TT * CC;     // 8,388,608 elems
    u16* Qb   = ws;              // Q; attn writes O here
    u16* Kbuf = ws + sz;         // K; reused for bf16 Wp after attn
    u16* Vtb  = ws + 2 * sz;     // V^T [B,H,D,T]   (ws total 48 MiB)

    u16* xb   = (u16*)d_out;     // squatters in d_out (dead by proj GEMM)
    u16* Wq16 = xb + sz;
    u16* Wk16 = Wq16 + (size_t)CC * CC;
    u16* Wv16 = Wk16 + (size_t)CC * CC;   // Wq16..Wv16 contiguous = W[3072][1024]

    static bool inited = false;
    if (!inited) {
        (void)hipFuncSetAttribute((const void*)gemmT<256, 128, 64, 64, 0>,
                                  hipFuncAttributeMaxDynamicSharedMemorySize, 73728);
        (void)hipFuncSetAttribute((const void*)gemmT<128, 128, 32, 64, 1>,
                                  hipFuncAttributeMaxDynamicSharedMemorySize, 49152);
        inited = true;
    }

    const int W8 = CC * CC / 8;      // 131072

    wcvtA<<<5632, 256, 0, stream>>>(x, Wq, Wk, Wv, xb, Wq16, Wk16, Wv16);

    gemmT<256, 128, 64, 64, 0><<<dim3(24, 32), 512, 73728, stream>>>(
        xb, Wq16, bq, bk, bv, Qb, Kbuf, Vtb, nullptr);

    attn<<<dim3(TT / 256, HH, BB), 512, 0, stream>>>(Qb, Kbuf, Vtb, mask, Qb);

    wcvt<<<512, 256, 0, stream>>>(Wp, Kbuf, W8);   // Kbuf dead after attn

    gemmT<128, 128, 32, 64, 1><<<dim3(8, 64), 512, 49152, stream>>>(
        Qb, Kbuf, bp, nullptr, nullptr, nullptr, nullptr, nullptr, (float*)d_out);
}